// Round 11
// baseline (2114.858 us; speedup 1.0000x reference)
//
#include <hip/hip_runtime.h>

typedef __attribute__((ext_vector_type(8))) short short8;
typedef __attribute__((ext_vector_type(4))) float f32x4;
typedef unsigned long long u64;

constexpr int NN = 100000;
constexpr int EE = 1600000;
constexpr int NF = 512;
constexpr int NH = 256;
constexpr int NC = 32;
constexpr int KP = 10;

__device__ __forceinline__ unsigned short f2bf(float f) {
  unsigned int u = __float_as_uint(f);
  u += 0x7FFFu + ((u >> 16) & 1u);   // round-to-nearest-even
  return (unsigned short)(u >> 16);
}
__device__ __forceinline__ float bf2f(unsigned short s) {
  return __uint_as_float(((unsigned int)s) << 16);
}
__device__ __forceinline__ int padc(int c) { return (c + 15) & ~15; }

__device__ __forceinline__ short8 cvt8(float4 a0, float4 a1) {
  union { unsigned int u[4]; short8 s; } r;
  asm("v_cvt_pk_bf16_f32 %0, %1, %2" : "=v"(r.u[0]) : "v"(a0.x), "v"(a0.y));
  asm("v_cvt_pk_bf16_f32 %0, %1, %2" : "=v"(r.u[1]) : "v"(a0.z), "v"(a0.w));
  asm("v_cvt_pk_bf16_f32 %0, %1, %2" : "=v"(r.u[2]) : "v"(a1.x), "v"(a1.y));
  asm("v_cvt_pk_bf16_f32 %0, %1, %2" : "=v"(r.u[3]) : "v"(a1.z), "v"(a1.w));
  return r.s;
}

// Barrier with LDS-only drain: keeps global loads (into registers) in flight
// across the barrier — avoids the compiler's vmcnt(0) drain of __syncthreads.
__device__ __forceinline__ void block_sync_lds() {
  asm volatile("s_waitcnt lgkmcnt(0)" ::: "memory");
  __builtin_amdgcn_s_barrier();
}

// ---- weight conversion: Wt[col][k]=bf(Ws[k][col]); Web[col][k]=bf(We[k][col])
__global__ void convwb_kernel(const float* __restrict__ Ws, const float* __restrict__ We,
                              unsigned short* __restrict__ Wt, unsigned short* __restrict__ Web) {
  int idx = blockIdx.x * 256 + threadIdx.x;      // 544*256 = 139264
  if (idx < 131072) {
    int col = idx >> 9, k = idx & 511;
    Wt[idx] = f2bf(Ws[(size_t)k * NH + col]);
  } else {
    int j = idx - 131072;
    int col = j >> 8, k = j & 255;
    Web[j] = f2bf(We[(size_t)k * NC + col]);
  }
}

// ---- GEMM1: H = relu(X[100000,512] @ W[512,256] + b), bf16 MFMA ------------
// R3 structure (best measured: 134 us). FROZEN: R1/R2/R4 redesigns regressed.
__global__ __launch_bounds__(256, 3) void gemm1_kernel(
    const float* __restrict__ X, const unsigned short* __restrict__ Wt,
    const float* __restrict__ bias, unsigned short* __restrict__ H) {
  constexpr int PAD = 36;
  __shared__ __align__(16) unsigned short Asm[2][128 * PAD];
  __shared__ __align__(16) unsigned short Bsm[2][128 * PAD];
  const int tid = threadIdx.x;
  const int lane = tid & 63;
  const int wave = tid >> 6;
  const int wm = wave >> 1, wn = wave & 1;
  const int l15 = lane & 15, kq = lane >> 4;
  const int m0 = (blockIdx.x >> 1) * 128;
  const int n0 = (blockIdx.x & 1) * 128;

  const int arl0 = tid >> 2, aq = tid & 3;
  int ar0 = m0 + arl0; if (ar0 >= NN) ar0 = NN - 1;
  int ar1 = m0 + arl0 + 64; if (ar1 >= NN) ar1 = NN - 1;
  const float* aptr0 = X + (size_t)ar0 * NF + aq * 8;
  const float* aptr1 = X + (size_t)ar1 * NF + aq * 8;
  const int awr0 = arl0 * PAD + aq * 8;
  const int awr1 = awr0 + 64 * PAD;
  const int bcl = tid >> 1, bh = tid & 1;
  const unsigned short* bptr = Wt + (size_t)(n0 + bcl) * NF + bh * 16;
  const int bwr = bcl * PAD + bh * 16;

  f32x4 acc[4][4];
#pragma unroll
  for (int m = 0; m < 4; m++)
#pragma unroll
    for (int n = 0; n < 4; n++) acc[m][n] = (f32x4)0.0f;

  float4 ra[3][4]; short8 rb0[3], rb1[3];   // depth-3 prefetch ring

#define LOADR(ks, j) do { \
    ra[j][0] = *reinterpret_cast<const float4*>(aptr0 + (ks) * 32); \
    ra[j][1] = *reinterpret_cast<const float4*>(aptr0 + (ks) * 32 + 4); \
    ra[j][2] = *reinterpret_cast<const float4*>(aptr1 + (ks) * 32); \
    ra[j][3] = *reinterpret_cast<const float4*>(aptr1 + (ks) * 32 + 4); \
    rb0[j] = *reinterpret_cast<const short8*>(bptr + (ks) * 32); \
    rb1[j] = *reinterpret_cast<const short8*>(bptr + (ks) * 32 + 8); \
  } while (0)

#define STAGE(b, j) do { \
    *reinterpret_cast<short8*>(&Asm[b][awr0]) = cvt8(ra[j][0], ra[j][1]); \
    *reinterpret_cast<short8*>(&Asm[b][awr1]) = cvt8(ra[j][2], ra[j][3]); \
    *reinterpret_cast<short8*>(&Bsm[b][bwr]) = rb0[j]; \
    *reinterpret_cast<short8*>(&Bsm[b][bwr + 8]) = rb1[j]; \
  } while (0)

#define COMPUTE(b) do { \
    short8 af[4], bfr[4]; \
    _Pragma("unroll") \
    for (int mi = 0; mi < 4; mi++) \
      af[mi] = *reinterpret_cast<const short8*>(&Asm[b][(wm * 64 + mi * 16 + l15) * PAD + kq * 8]); \
    _Pragma("unroll") \
    for (int ni = 0; ni < 4; ni++) \
      bfr[ni] = *reinterpret_cast<const short8*>(&Bsm[b][(wn * 64 + ni * 16 + l15) * PAD + kq * 8]); \
    _Pragma("unroll") \
    for (int mi = 0; mi < 4; mi++) \
      _Pragma("unroll") \
      for (int ni = 0; ni < 4; ni++) \
        acc[mi][ni] = __builtin_amdgcn_mfma_f32_16x16x32_bf16(af[mi], bfr[ni], acc[mi][ni], 0, 0, 0); \
  } while (0)

  LOADR(0, 0);
  LOADR(1, 1);
  LOADR(2, 2);
  STAGE(0, 0);
  block_sync_lds();

#pragma unroll
  for (int p = 0; p < 16; p++) {
    if (p + 3 < 16) LOADR(p + 3, (p + 3) % 3);
    COMPUTE(p & 1);
    if (p + 1 < 16) STAGE((p + 1) & 1, (p + 1) % 3);
    block_sync_lds();
  }
#undef LOADR
#undef STAGE
#undef COMPUTE

  // epilogue: bias + relu, store bf16.  C/D layout: col=lane&15, row=(lane>>4)*4+i
#pragma unroll
  for (int ni = 0; ni < 4; ni++) {
    int col = n0 + wn * 64 + ni * 16 + l15;
    float bsv = bias[col];
#pragma unroll
    for (int mi = 0; mi < 4; mi++) {
      int rb2 = m0 + wm * 64 + mi * 16 + kq * 4;
#pragma unroll
      for (int i = 0; i < 4; i++) {
        int r = rb2 + i;
        if (r < NN) {
          float v = acc[mi][ni][i] + bsv;
          H[(size_t)r * NH + col] = f2bf(v > 0.f ? v : 0.f);
        }
      }
    }
  }
}

// ---- GEMM2 (MFMA): h2 = relu(H @ We + be); x0b = bf16(h2); out = t0*h2 -----
__global__ __launch_bounds__(256) void gemm2_kernel(
    const unsigned short* __restrict__ H, const unsigned short* __restrict__ Web,
    const float* __restrict__ be, const float* __restrict__ temp,
    unsigned short* __restrict__ x0b, float* __restrict__ out) {
  const int tid = threadIdx.x;
  const int lane = tid & 63;
  const int wave = tid >> 6;
  const int l15 = lane & 15, kq = lane >> 4;
  const int rbase = blockIdx.x * 64 + wave * 16;
  int rr = rbase + l15; if (rr >= NN) rr = NN - 1;
  const unsigned short* hrow = H + (size_t)rr * NH + kq * 8;
  const unsigned short* wrow = Web + (size_t)l15 * 256 + kq * 8;

  f32x4 acc[2];
  acc[0] = (f32x4)0.0f; acc[1] = (f32x4)0.0f;
#pragma unroll
  for (int ks = 0; ks < 8; ks++) {
    short8 a = *reinterpret_cast<const short8*>(hrow + ks * 32);
    short8 b0 = *reinterpret_cast<const short8*>(wrow + ks * 32);
    short8 b1 = *reinterpret_cast<const short8*>(wrow + 16 * 256 + ks * 32);
    acc[0] = __builtin_amdgcn_mfma_f32_16x16x32_bf16(a, b0, acc[0], 0, 0, 0);
    acc[1] = __builtin_amdgcn_mfma_f32_16x16x32_bf16(a, b1, acc[1], 0, 0, 0);
  }
  const float t0 = temp[0];
#pragma unroll
  for (int nt = 0; nt < 2; nt++) {
    int col = nt * 16 + l15;
    float bv = be[col];
#pragma unroll
    for (int i = 0; i < 4; i++) {
      int row = rbase + kq * 4 + i;
      if (row < NN) {
        float v = acc[nt][i] + bv;
        v = v > 0.f ? v : 0.f;
        x0b[(size_t)row * NC + col] = f2bf(v);
        out[(size_t)row * NC + col] = t0 * v;
      }
    }
  }
}

// ---- graph normalization + CSR build ---------------------------------------
// dc[i]: bits[63:44] = count, bits[43:0] = fixed-point deg (scale 2^32)
// Also zeroes the degree-bucket histogram (bcnt[64]).
__global__ void node_init_kernel(u64* dc, int* bcnt) {
  int i = blockIdx.x * 256 + threadIdx.x;
  if (i < 64) bcnt[i] = 0;
  if (i < NN) dc[i] = (1ULL << 44) | (1ULL << 32);   // self-loop: cnt=1, deg=1.0
}

__global__ void edge_deg_kernel(const int* __restrict__ ei, const float* __restrict__ ew,
                                u64* dc) {
  int e = blockIdx.x * 256 + threadIdx.x;
  if (e < EE) {
    int col = ei[EE + e];
    u64 v = (1ULL << 44) | (u64)((double)ew[e] * 4294967296.0);
    atomicAdd(&dc[col], v);
  }
}

__global__ void dis_kernel(const u64* __restrict__ dc, float* __restrict__ dis,
                           int* __restrict__ cnt) {
  int i = blockIdx.x * 256 + threadIdx.x;
  if (i < NN) {
    u64 v = dc[i];
    cnt[i] = (int)(v >> 44);
    float deg = (float)((double)(v & 0xFFFFFFFFFFFULL) * (1.0 / 4294967296.0));
    dis[i] = rsqrtf(deg);
  }
}

// ---- degree-bucket counting sort (kills spmm intra-wave divergence) --------
__global__ void bhist_kernel(const int* __restrict__ cnt, int* bcnt) {
  int i = blockIdx.x * 256 + threadIdx.x;
  if (i < NN) {
    int b = padc(cnt[i]) >> 4; if (b > 63) b = 63;
    atomicAdd(&bcnt[b], 1);
  }
}

__global__ void bscan_kernel(const int* __restrict__ bcnt, int* bcur) {
  if (threadIdx.x == 0) {
    int run = 0;
    for (int b = 0; b < 64; b++) { bcur[b] = run; run += bcnt[b]; }
  }
}

__global__ void bscatter_kernel(const int* __restrict__ cnt, int* bcur,
                                int* __restrict__ nidx) {
  int i = blockIdx.x * 256 + threadIdx.x;
  if (i < NN) {
    int b = padc(cnt[i]) >> 4; if (b > 63) b = 63;
    nidx[atomicAdd(&bcur[b], 1)] = i;
  }
}

// scans use PADDED counts (mult of 16) so every CSR list is a whole number of
// 8-batches in spmm (no serial remainder tails).
__global__ void scan1_kernel(const int* __restrict__ cnt, int* bsum) {
  __shared__ int ws[4];
  const int tid = threadIdx.x;
  int base = blockIdx.x * 1024 + tid * 4;
  int s = 0;
#pragma unroll
  for (int j = 0; j < 4; j++) { int i = base + j; if (i < NN) s += padc(cnt[i]); }
  for (int off = 32; off > 0; off >>= 1) s += __shfl_down(s, off);
  if ((tid & 63) == 0) ws[tid >> 6] = s;
  __syncthreads();
  if (tid == 0) bsum[blockIdx.x] = ws[0] + ws[1] + ws[2] + ws[3];
}

__global__ void scan2_kernel(const int* __restrict__ bsum, int* bofs, int* offs) {
  if (threadIdx.x == 0) {
    int run = 0;
    for (int i = 0; i < 98; i++) { bofs[i] = run; run += bsum[i]; }
    offs[NN] = run;
  }
}

__global__ void scan3_kernel(const int* __restrict__ cnt, const int* __restrict__ bofs,
                             int* offs, int* cursor) {
  __shared__ int wsum[4];
  const int tid = threadIdx.x;
  const int lane = tid & 63, wv = tid >> 6;
  int base = blockIdx.x * 1024 + tid * 4;
  int v[4]; int s = 0;
#pragma unroll
  for (int j = 0; j < 4; j++) { int i = base + j; v[j] = (i < NN) ? padc(cnt[i]) : 0; s += v[j]; }
  int incl = s;
  for (int off = 1; off < 64; off <<= 1) {
    int t = __shfl_up(incl, off);
    if (lane >= off) incl += t;
  }
  if (lane == 63) wsum[wv] = incl;
  __syncthreads();
  int woff = bofs[blockIdx.x];
  for (int w = 0; w < wv; w++) woff += wsum[w];
  int excl = woff + incl - s;
#pragma unroll
  for (int j = 0; j < 4; j++) {
    int i = base + j;
    if (i < NN) { offs[i] = excl; cursor[i] = excl; }
    excl += v[j];
  }
}

// pk[slot]: low 32 = row index, high 32 = fp32 weight bits
__global__ void fill_kernel(const int* __restrict__ ei, const float* __restrict__ ew,
                            const float* __restrict__ dis, int* cursor,
                            u64* __restrict__ pk) {
  int t = blockIdx.x * 256 + threadIdx.x;
  if (t < EE) {
    int r = ei[t], c = ei[EE + t];
    int slot = atomicAdd(&cursor[c], 1);
    unsigned int wb = __float_as_uint(dis[r] * ew[t] * dis[c]);
    pk[slot] = (u64)(unsigned int)r | ((u64)wb << 32);
  } else if (t < EE + NN) {
    int i = t - EE;
    int slot = atomicAdd(&cursor[i], 1);
    float d = dis[i];
    unsigned int wb = __float_as_uint(d * d);
    pk[slot] = (u64)(unsigned int)i | ((u64)wb << 32);
  }
}

// zero-fill the padding gap [cursor[i], offs[i+1]) with row=0, weight=0
__global__ void pad_kernel(const int* __restrict__ cursor, const int* __restrict__ offs,
                           u64* __restrict__ pk) {
  int i = blockIdx.x * 256 + threadIdx.x;
  if (i < NN) {
    int j = cursor[i], e = offs[i + 1];
    for (; j < e; j++) pk[j] = 0;
  }
}

// ---- SpMM (bf16 xk): xout = A*xin ------------------------------------------
// R9 shape (verified fastest): 8 lanes/node, 8B gathers, batch 8, 3125 blocks.
// + degree-sorted node order via nidx (waves process same-degree nodes ->
//   no intra-wave divergence) and pk loads paired as 16B.
__global__ __launch_bounds__(256) void spmm_kernel(
    const int* __restrict__ offs, const u64* __restrict__ pk,
    const int* __restrict__ nidx,
    const unsigned short* __restrict__ xin, unsigned short* __restrict__ xout) {
  const int tid = threadIdx.x;
  const int ni = blockIdx.x * 32 + (tid >> 3);     // 3125*32 = 100000 exact
  const int fq = (tid & 7) * 4;                    // feature quad base
  const int node = nidx[ni];
  const int s = offs[node], e = offs[node + 1];
  float a0 = 0.f, a1 = 0.f, a2 = 0.f, a3 = 0.f;
  for (int j = s; j < e; j += 8) {
    ulonglong2 p01 = *reinterpret_cast<const ulonglong2*>(pk + j);
    ulonglong2 p23 = *reinterpret_cast<const ulonglong2*>(pk + j + 2);
    ulonglong2 p45 = *reinterpret_cast<const ulonglong2*>(pk + j + 4);
    ulonglong2 p67 = *reinterpret_cast<const ulonglong2*>(pk + j + 6);
    const u64 p[8] = {p01.x, p01.y, p23.x, p23.y, p45.x, p45.y, p67.x, p67.y};
    u64 q[8];
#pragma unroll
    for (int i = 0; i < 8; i++)
      q[i] = *reinterpret_cast<const u64*>(xin + (size_t)(unsigned int)p[i] * NC + fq);
#pragma unroll
    for (int i = 0; i < 8; i++) {
      const float w = __uint_as_float((unsigned int)(p[i] >> 32));
      a0 += w * bf2f((unsigned short)(q[i]));
      a1 += w * bf2f((unsigned short)(q[i] >> 16));
      a2 += w * bf2f((unsigned short)(q[i] >> 32));
      a3 += w * bf2f((unsigned short)(q[i] >> 48));
    }
  }
  // pack 4 bf16 (RNE via cvt_pk) and store 8B
  unsigned int lo, hi;
  asm("v_cvt_pk_bf16_f32 %0, %1, %2" : "=v"(lo) : "v"(a0), "v"(a1));
  asm("v_cvt_pk_bf16_f32 %0, %1, %2" : "=v"(hi) : "v"(a2), "v"(a3));
  *reinterpret_cast<u64*>(xout + (size_t)node * NC + fq) =
      (u64)lo | ((u64)hi << 32);
}

// ---- final weighted sum: out += sum_k temp[k+1] * xk_k (8 feats/thread) ----
__global__ __launch_bounds__(256) void wsum_kernel(
    const unsigned short* __restrict__ S07,   // slices 0..7 (H region)
    const unsigned short* __restrict__ S8, const unsigned short* __restrict__ S9,
    float* __restrict__ out, const float* __restrict__ temp) {
  int t8 = blockIdx.x * 256 + threadIdx.x;    // 1563*256 = 400128 >= 400000
  if (t8 >= NN * NC / 8) return;
  const size_t base = (size_t)t8 * 8;
  float s[8];
  float4 o0 = *reinterpret_cast<const float4*>(out + base);
  float4 o1 = *reinterpret_cast<const float4*>(out + base + 4);
  s[0] = o0.x; s[1] = o0.y; s[2] = o0.z; s[3] = o0.w;
  s[4] = o1.x; s[5] = o1.y; s[6] = o1.z; s[7] = o1.w;
#pragma unroll
  for (int k = 0; k < 8; k++) {
    const float tk = temp[k + 1];
    short8 v = *reinterpret_cast<const short8*>(S07 + (size_t)k * NN * NC + base);
#pragma unroll
    for (int t = 0; t < 8; t++) s[t] += tk * bf2f((unsigned short)v[t]);
  }
  {
    const float tk = temp[9];
    short8 v = *reinterpret_cast<const short8*>(S8 + base);
#pragma unroll
    for (int t = 0; t < 8; t++) s[t] += tk * bf2f((unsigned short)v[t]);
  }
  {
    const float tk = temp[10];
    short8 v = *reinterpret_cast<const short8*>(S9 + base);
#pragma unroll
    for (int t = 0; t < 8; t++) s[t] += tk * bf2f((unsigned short)v[t]);
  }
  *reinterpret_cast<float4*>(out + base) = make_float4(s[0], s[1], s[2], s[3]);
  *reinterpret_cast<float4*>(out + base + 4) = make_float4(s[4], s[5], s[6], s[7]);
}

extern "C" void kernel_launch(void* const* d_in, const int* in_sizes, int n_in,
                              void* d_out, int out_size, void* d_ws, size_t ws_size,
                              hipStream_t stream) {
  const float* X    = (const float*)d_in[0];
  const float* EA   = (const float*)d_in[1];
  const float* Ws   = (const float*)d_in[2];
  const float* bs   = (const float*)d_in[3];
  const float* We   = (const float*)d_in[4];
  const float* be   = (const float*)d_in[5];
  const float* temp = (const float*)d_in[6];
  const int*   ei   = (const int*)d_in[7];
  float* out = (float*)d_out;

  size_t off = 0;
  auto alloc = [&](size_t n) { void* p = (char*)d_ws + off; off += (n + 255) & ~(size_t)255; return p; };
  unsigned short* Wt  = (unsigned short*)alloc((size_t)NF * NH * 2);   // 256 KB
  unsigned short* Web = (unsigned short*)alloc((size_t)NH * NC * 2);   // 16 KB
  unsigned short* H   = (unsigned short*)alloc((size_t)NN * NH * 2);   // 51.2 MB = slices 0..7
  unsigned short* x0b = (unsigned short*)alloc((size_t)NN * NC * 2);   // 6.4 MB (gemm2 out)
  unsigned short* xk8 = (unsigned short*)alloc((size_t)NN * NC * 2);   // slice 8
  unsigned short* xk9 = (unsigned short*)alloc((size_t)NN * NC * 2);   // slice 9
  u64*   dc   = (u64*)alloc((size_t)NN * 8);                           // 800 KB
  float* dis  = (float*)alloc((size_t)NN * 4);
  int*   cnt  = (int*)alloc((size_t)NN * 4);
  int*   offs = (int*)alloc((size_t)(NN + 1) * 4);
  int*   cursor = (int*)alloc((size_t)NN * 4);
  int*   bsum = (int*)alloc(98 * 4);
  int*   bofs = (int*)alloc(98 * 4);
  int*   bcnt = (int*)alloc(64 * 4);
  int*   bcur = (int*)alloc(64 * 4);
  int*   nidx = (int*)alloc((size_t)NN * 4);
  u64*   pk   = (u64*)alloc((size_t)(EE + 16 * NN) * 8);               // 25.6 MB (padded)

  // MLP front-end
  convwb_kernel<<<544, 256, 0, stream>>>(Ws, We, Wt, Web);
  gemm1_kernel<<<1564, 256, 0, stream>>>(X, Wt, bs, H);
  gemm2_kernel<<<1563, 256, 0, stream>>>(H, Web, be, temp, x0b, out);

  // gcn_norm + padded CSR build (by col, so SpMM is atomic-free)
  node_init_kernel<<<391, 256, 0, stream>>>(dc, bcnt);
  edge_deg_kernel<<<6250, 256, 0, stream>>>(ei, EA, dc);
  dis_kernel<<<391, 256, 0, stream>>>(dc, dis, cnt);
  bhist_kernel<<<391, 256, 0, stream>>>(cnt, bcnt);
  bscan_kernel<<<1, 64, 0, stream>>>(bcnt, bcur);
  bscatter_kernel<<<391, 256, 0, stream>>>(cnt, bcur, nidx);
  scan1_kernel<<<98, 256, 0, stream>>>(cnt, bsum);
  scan2_kernel<<<1, 64, 0, stream>>>(bsum, bofs, offs);
  scan3_kernel<<<98, 256, 0, stream>>>(cnt, bofs, offs, cursor);
  fill_kernel<<<6641, 256, 0, stream>>>(ei, EA, dis, cursor, pk);
  pad_kernel<<<391, 256, 0, stream>>>(cursor, offs, pk);

  // K=10 propagation; slice k lives in H (k<8) else xk8/xk9.  NOTE: H is dead
  // after gemm2, so its 51.2 MB is reused as 8 xk slices.
  auto slice = [&](int k) -> unsigned short* {
    return (k < 8) ? H + (size_t)k * NN * NC : (k == 8 ? xk8 : xk9);
  };
  const unsigned short* xin = x0b;
  for (int k = 0; k < KP; k++) {
    spmm_kernel<<<3125, 256, 0, stream>>>(offs, pk, nidx, xin, slice(k));
    xin = slice(k);
  }
  wsum_kernel<<<1563, 256, 0, stream>>>(H, xk8, xk9, out, temp);
}

// Round 12
// 539.297 us; speedup vs baseline: 3.9215x; 3.9215x over previous
//
#include <hip/hip_runtime.h>

typedef __attribute__((ext_vector_type(8))) short short8;
typedef __attribute__((ext_vector_type(4))) float f32x4;
typedef unsigned long long u64;

constexpr int NN = 100000;
constexpr int EE = 1600000;
constexpr int NF = 512;
constexpr int NH = 256;
constexpr int NC = 32;
constexpr int KP = 10;

__device__ __forceinline__ unsigned short f2bf(float f) {
  unsigned int u = __float_as_uint(f);
  u += 0x7FFFu + ((u >> 16) & 1u);   // round-to-nearest-even
  return (unsigned short)(u >> 16);
}
__device__ __forceinline__ float bf2f(unsigned short s) {
  return __uint_as_float(((unsigned int)s) << 16);
}
// pad to 8: whole number of 8-batches in spmm, ~18% less pad waste than 16
__device__ __forceinline__ int padc(int c) { return (c + 7) & ~7; }

__device__ __forceinline__ short8 cvt8(float4 a0, float4 a1) {
  union { unsigned int u[4]; short8 s; } r;
  asm("v_cvt_pk_bf16_f32 %0, %1, %2" : "=v"(r.u[0]) : "v"(a0.x), "v"(a0.y));
  asm("v_cvt_pk_bf16_f32 %0, %1, %2" : "=v"(r.u[1]) : "v"(a0.z), "v"(a0.w));
  asm("v_cvt_pk_bf16_f32 %0, %1, %2" : "=v"(r.u[2]) : "v"(a1.x), "v"(a1.y));
  asm("v_cvt_pk_bf16_f32 %0, %1, %2" : "=v"(r.u[3]) : "v"(a1.z), "v"(a1.w));
  return r.s;
}

// Barrier with LDS-only drain: keeps global loads (into registers) in flight
// across the barrier — avoids the compiler's vmcnt(0) drain of __syncthreads.
__device__ __forceinline__ void block_sync_lds() {
  asm volatile("s_waitcnt lgkmcnt(0)" ::: "memory");
  __builtin_amdgcn_s_barrier();
}

// ---- weight conversion: Wt[col][k]=bf(Ws[k][col]); Web[col][k]=bf(We[k][col])
__global__ void convwb_kernel(const float* __restrict__ Ws, const float* __restrict__ We,
                              unsigned short* __restrict__ Wt, unsigned short* __restrict__ Web) {
  int idx = blockIdx.x * 256 + threadIdx.x;      // 544*256 = 139264
  if (idx < 131072) {
    int col = idx >> 9, k = idx & 511;
    Wt[idx] = f2bf(Ws[(size_t)k * NH + col]);
  } else {
    int j = idx - 131072;
    int col = j >> 8, k = j & 255;
    Web[j] = f2bf(We[(size_t)k * NC + col]);
  }
}

// ---- GEMM1: H = relu(X[100000,512] @ W[512,256] + b), bf16 MFMA ------------
// R3 structure (best measured: 134 us). FROZEN: R1/R2/R4 redesigns regressed.
__global__ __launch_bounds__(256, 3) void gemm1_kernel(
    const float* __restrict__ X, const unsigned short* __restrict__ Wt,
    const float* __restrict__ bias, unsigned short* __restrict__ H) {
  constexpr int PAD = 36;
  __shared__ __align__(16) unsigned short Asm[2][128 * PAD];
  __shared__ __align__(16) unsigned short Bsm[2][128 * PAD];
  const int tid = threadIdx.x;
  const int lane = tid & 63;
  const int wave = tid >> 6;
  const int wm = wave >> 1, wn = wave & 1;
  const int l15 = lane & 15, kq = lane >> 4;
  const int m0 = (blockIdx.x >> 1) * 128;
  const int n0 = (blockIdx.x & 1) * 128;

  const int arl0 = tid >> 2, aq = tid & 3;
  int ar0 = m0 + arl0; if (ar0 >= NN) ar0 = NN - 1;
  int ar1 = m0 + arl0 + 64; if (ar1 >= NN) ar1 = NN - 1;
  const float* aptr0 = X + (size_t)ar0 * NF + aq * 8;
  const float* aptr1 = X + (size_t)ar1 * NF + aq * 8;
  const int awr0 = arl0 * PAD + aq * 8;
  const int awr1 = awr0 + 64 * PAD;
  const int bcl = tid >> 1, bh = tid & 1;
  const unsigned short* bptr = Wt + (size_t)(n0 + bcl) * NF + bh * 16;
  const int bwr = bcl * PAD + bh * 16;

  f32x4 acc[4][4];
#pragma unroll
  for (int m = 0; m < 4; m++)
#pragma unroll
    for (int n = 0; n < 4; n++) acc[m][n] = (f32x4)0.0f;

  float4 ra[3][4]; short8 rb0[3], rb1[3];   // depth-3 prefetch ring

#define LOADR(ks, j) do { \
    ra[j][0] = *reinterpret_cast<const float4*>(aptr0 + (ks) * 32); \
    ra[j][1] = *reinterpret_cast<const float4*>(aptr0 + (ks) * 32 + 4); \
    ra[j][2] = *reinterpret_cast<const float4*>(aptr1 + (ks) * 32); \
    ra[j][3] = *reinterpret_cast<const float4*>(aptr1 + (ks) * 32 + 4); \
    rb0[j] = *reinterpret_cast<const short8*>(bptr + (ks) * 32); \
    rb1[j] = *reinterpret_cast<const short8*>(bptr + (ks) * 32 + 8); \
  } while (0)

#define STAGE(b, j) do { \
    *reinterpret_cast<short8*>(&Asm[b][awr0]) = cvt8(ra[j][0], ra[j][1]); \
    *reinterpret_cast<short8*>(&Asm[b][awr1]) = cvt8(ra[j][2], ra[j][3]); \
    *reinterpret_cast<short8*>(&Bsm[b][bwr]) = rb0[j]; \
    *reinterpret_cast<short8*>(&Bsm[b][bwr + 8]) = rb1[j]; \
  } while (0)

#define COMPUTE(b) do { \
    short8 af[4], bfr[4]; \
    _Pragma("unroll") \
    for (int mi = 0; mi < 4; mi++) \
      af[mi] = *reinterpret_cast<const short8*>(&Asm[b][(wm * 64 + mi * 16 + l15) * PAD + kq * 8]); \
    _Pragma("unroll") \
    for (int ni = 0; ni < 4; ni++) \
      bfr[ni] = *reinterpret_cast<const short8*>(&Bsm[b][(wn * 64 + ni * 16 + l15) * PAD + kq * 8]); \
    _Pragma("unroll") \
    for (int mi = 0; mi < 4; mi++) \
      _Pragma("unroll") \
      for (int ni = 0; ni < 4; ni++) \
        acc[mi][ni] = __builtin_amdgcn_mfma_f32_16x16x32_bf16(af[mi], bfr[ni], acc[mi][ni], 0, 0, 0); \
  } while (0)

  LOADR(0, 0);
  LOADR(1, 1);
  LOADR(2, 2);
  STAGE(0, 0);
  block_sync_lds();

#pragma unroll
  for (int p = 0; p < 16; p++) {
    if (p + 3 < 16) LOADR(p + 3, (p + 3) % 3);
    COMPUTE(p & 1);
    if (p + 1 < 16) STAGE((p + 1) & 1, (p + 1) % 3);
    block_sync_lds();
  }
#undef LOADR
#undef STAGE
#undef COMPUTE

  // epilogue: bias + relu, store bf16.  C/D layout: col=lane&15, row=(lane>>4)*4+i
#pragma unroll
  for (int ni = 0; ni < 4; ni++) {
    int col = n0 + wn * 64 + ni * 16 + l15;
    float bsv = bias[col];
#pragma unroll
    for (int mi = 0; mi < 4; mi++) {
      int rb2 = m0 + wm * 64 + mi * 16 + kq * 4;
#pragma unroll
      for (int i = 0; i < 4; i++) {
        int r = rb2 + i;
        if (r < NN) {
          float v = acc[mi][ni][i] + bsv;
          H[(size_t)r * NH + col] = f2bf(v > 0.f ? v : 0.f);
        }
      }
    }
  }
}

// ---- GEMM2 (MFMA): h2 = relu(H @ We + be); x0b = bf16(h2); out = t0*h2 -----
__global__ __launch_bounds__(256) void gemm2_kernel(
    const unsigned short* __restrict__ H, const unsigned short* __restrict__ Web,
    const float* __restrict__ be, const float* __restrict__ temp,
    unsigned short* __restrict__ x0b, float* __restrict__ out) {
  const int tid = threadIdx.x;
  const int lane = tid & 63;
  const int wave = tid >> 6;
  const int l15 = lane & 15, kq = lane >> 4;
  const int rbase = blockIdx.x * 64 + wave * 16;
  int rr = rbase + l15; if (rr >= NN) rr = NN - 1;
  const unsigned short* hrow = H + (size_t)rr * NH + kq * 8;
  const unsigned short* wrow = Web + (size_t)l15 * 256 + kq * 8;

  f32x4 acc[2];
  acc[0] = (f32x4)0.0f; acc[1] = (f32x4)0.0f;
#pragma unroll
  for (int ks = 0; ks < 8; ks++) {
    short8 a = *reinterpret_cast<const short8*>(hrow + ks * 32);
    short8 b0 = *reinterpret_cast<const short8*>(wrow + ks * 32);
    short8 b1 = *reinterpret_cast<const short8*>(wrow + 16 * 256 + ks * 32);
    acc[0] = __builtin_amdgcn_mfma_f32_16x16x32_bf16(a, b0, acc[0], 0, 0, 0);
    acc[1] = __builtin_amdgcn_mfma_f32_16x16x32_bf16(a, b1, acc[1], 0, 0, 0);
  }
  const float t0 = temp[0];
#pragma unroll
  for (int nt = 0; nt < 2; nt++) {
    int col = nt * 16 + l15;
    float bv = be[col];
#pragma unroll
    for (int i = 0; i < 4; i++) {
      int row = rbase + kq * 4 + i;
      if (row < NN) {
        float v = acc[nt][i] + bv;
        v = v > 0.f ? v : 0.f;
        x0b[(size_t)row * NC + col] = f2bf(v);
        out[(size_t)row * NC + col] = t0 * v;
      }
    }
  }
}

// ---- graph normalization + CSR build ---------------------------------------
// dc[i]: bits[63:44] = count, bits[43:0] = fixed-point deg (scale 2^32)
__global__ void node_init_kernel(u64* dc) {
  int i = blockIdx.x * 256 + threadIdx.x;
  if (i < NN) dc[i] = (1ULL << 44) | (1ULL << 32);   // self-loop: cnt=1, deg=1.0
}

__global__ void edge_deg_kernel(const int* __restrict__ ei, const float* __restrict__ ew,
                                u64* dc) {
  int e = blockIdx.x * 256 + threadIdx.x;
  if (e < EE) {
    int col = ei[EE + e];
    u64 v = (1ULL << 44) | (u64)((double)ew[e] * 4294967296.0);
    atomicAdd(&dc[col], v);
  }
}

__global__ void dis_kernel(const u64* __restrict__ dc, float* __restrict__ dis,
                           int* __restrict__ cnt) {
  int i = blockIdx.x * 256 + threadIdx.x;
  if (i < NN) {
    u64 v = dc[i];
    cnt[i] = (int)(v >> 44);
    float deg = (float)((double)(v & 0xFFFFFFFFFFFULL) * (1.0 / 4294967296.0));
    dis[i] = rsqrtf(deg);
  }
}

// scans use PADDED counts (mult of 8) so every CSR list is a whole number of
// 8-batches in spmm (no serial remainder tails).
__global__ void scan1_kernel(const int* __restrict__ cnt, int* bsum) {
  __shared__ int ws[4];
  const int tid = threadIdx.x;
  int base = blockIdx.x * 1024 + tid * 4;
  int s = 0;
#pragma unroll
  for (int j = 0; j < 4; j++) { int i = base + j; if (i < NN) s += padc(cnt[i]); }
  for (int off = 32; off > 0; off >>= 1) s += __shfl_down(s, off);
  if ((tid & 63) == 0) ws[tid >> 6] = s;
  __syncthreads();
  if (tid == 0) bsum[blockIdx.x] = ws[0] + ws[1] + ws[2] + ws[3];
}

__global__ void scan2_kernel(const int* __restrict__ bsum, int* bofs, int* offs) {
  if (threadIdx.x == 0) {
    int run = 0;
    for (int i = 0; i < 98; i++) { bofs[i] = run; run += bsum[i]; }
    offs[NN] = run;
  }
}

__global__ void scan3_kernel(const int* __restrict__ cnt, const int* __restrict__ bofs,
                             int* offs, int* cursor) {
  __shared__ int wsum[4];
  const int tid = threadIdx.x;
  const int lane = tid & 63, wv = tid >> 6;
  int base = blockIdx.x * 1024 + tid * 4;
  int v[4]; int s = 0;
#pragma unroll
  for (int j = 0; j < 4; j++) { int i = base + j; v[j] = (i < NN) ? padc(cnt[i]) : 0; s += v[j]; }
  int incl = s;
  for (int off = 1; off < 64; off <<= 1) {
    int t = __shfl_up(incl, off);
    if (lane >= off) incl += t;
  }
  if (lane == 63) wsum[wv] = incl;
  __syncthreads();
  int woff = bofs[blockIdx.x];
  for (int w = 0; w < wv; w++) woff += wsum[w];
  int excl = woff + incl - s;
#pragma unroll
  for (int j = 0; j < 4; j++) {
    int i = base + j;
    if (i < NN) { offs[i] = excl; cursor[i] = excl; }
    excl += v[j];
  }
}

// pk[slot]: low 32 = row index, high 32 = fp32 weight bits
__global__ void fill_kernel(const int* __restrict__ ei, const float* __restrict__ ew,
                            const float* __restrict__ dis, int* cursor,
                            u64* __restrict__ pk) {
  int t = blockIdx.x * 256 + threadIdx.x;
  if (t < EE) {
    int r = ei[t], c = ei[EE + t];
    int slot = atomicAdd(&cursor[c], 1);
    unsigned int wb = __float_as_uint(dis[r] * ew[t] * dis[c]);
    pk[slot] = (u64)(unsigned int)r | ((u64)wb << 32);
  } else if (t < EE + NN) {
    int i = t - EE;
    int slot = atomicAdd(&cursor[i], 1);
    float d = dis[i];
    unsigned int wb = __float_as_uint(d * d);
    pk[slot] = (u64)(unsigned int)i | ((u64)wb << 32);
  }
}

// zero-fill the padding gap [cursor[i], offs[i+1]) with row=0, weight=0
__global__ void pad_kernel(const int* __restrict__ cursor, const int* __restrict__ offs,
                           u64* __restrict__ pk) {
  int i = blockIdx.x * 256 + threadIdx.x;
  if (i < NN) {
    int j = cursor[i], e = offs[i + 1];
    for (; j < e; j++) pk[j] = 0;
  }
}

// ---- SpMM (bf16 xk): xout = A*xin ------------------------------------------
// R9 shape (verified fastest): 8 lanes/node, 8B gathers, batch 8, 3125 blocks.
// pk loads paired as 16B (8-aligned offsets keep alignment).
__global__ __launch_bounds__(256) void spmm_kernel(
    const int* __restrict__ offs, const u64* __restrict__ pk,
    const unsigned short* __restrict__ xin, unsigned short* __restrict__ xout) {
  const int tid = threadIdx.x;
  const int node = blockIdx.x * 32 + (tid >> 3);   // 3125*32 = 100000 exact
  const int fq = (tid & 7) * 4;                    // feature quad base
  const int s = offs[node], e = offs[node + 1];
  float a0 = 0.f, a1 = 0.f, a2 = 0.f, a3 = 0.f;
  for (int j = s; j < e; j += 8) {
    ulonglong2 p01 = *reinterpret_cast<const ulonglong2*>(pk + j);
    ulonglong2 p23 = *reinterpret_cast<const ulonglong2*>(pk + j + 2);
    ulonglong2 p45 = *reinterpret_cast<const ulonglong2*>(pk + j + 4);
    ulonglong2 p67 = *reinterpret_cast<const ulonglong2*>(pk + j + 6);
    const u64 p[8] = {p01.x, p01.y, p23.x, p23.y, p45.x, p45.y, p67.x, p67.y};
    u64 q[8];
#pragma unroll
    for (int i = 0; i < 8; i++)
      q[i] = *reinterpret_cast<const u64*>(xin + (size_t)(unsigned int)p[i] * NC + fq);
#pragma unroll
    for (int i = 0; i < 8; i++) {
      const float w = __uint_as_float((unsigned int)(p[i] >> 32));
      a0 += w * bf2f((unsigned short)(q[i]));
      a1 += w * bf2f((unsigned short)(q[i] >> 16));
      a2 += w * bf2f((unsigned short)(q[i] >> 32));
      a3 += w * bf2f((unsigned short)(q[i] >> 48));
    }
  }
  // pack 4 bf16 (RNE via cvt_pk) and store 8B
  unsigned int lo, hi;
  asm("v_cvt_pk_bf16_f32 %0, %1, %2" : "=v"(lo) : "v"(a0), "v"(a1));
  asm("v_cvt_pk_bf16_f32 %0, %1, %2" : "=v"(hi) : "v"(a2), "v"(a3));
  *reinterpret_cast<u64*>(xout + (size_t)node * NC + fq) =
      (u64)lo | ((u64)hi << 32);
}

// ---- final weighted sum: out += sum_k temp[k+1] * xk_k (8 feats/thread) ----
__global__ __launch_bounds__(256) void wsum_kernel(
    const unsigned short* __restrict__ S07,   // slices 0..7 (H region)
    const unsigned short* __restrict__ S8, const unsigned short* __restrict__ S9,
    float* __restrict__ out, const float* __restrict__ temp) {
  int t8 = blockIdx.x * 256 + threadIdx.x;    // 1563*256 = 400128 >= 400000
  if (t8 >= NN * NC / 8) return;
  const size_t base = (size_t)t8 * 8;
  float s[8];
  float4 o0 = *reinterpret_cast<const float4*>(out + base);
  float4 o1 = *reinterpret_cast<const float4*>(out + base + 4);
  s[0] = o0.x; s[1] = o0.y; s[2] = o0.z; s[3] = o0.w;
  s[4] = o1.x; s[5] = o1.y; s[6] = o1.z; s[7] = o1.w;
#pragma unroll
  for (int k = 0; k < 8; k++) {
    const float tk = temp[k + 1];
    short8 v = *reinterpret_cast<const short8*>(S07 + (size_t)k * NN * NC + base);
#pragma unroll
    for (int t = 0; t < 8; t++) s[t] += tk * bf2f((unsigned short)v[t]);
  }
  {
    const float tk = temp[9];
    short8 v = *reinterpret_cast<const short8*>(S8 + base);
#pragma unroll
    for (int t = 0; t < 8; t++) s[t] += tk * bf2f((unsigned short)v[t]);
  }
  {
    const float tk = temp[10];
    short8 v = *reinterpret_cast<const short8*>(S9 + base);
#pragma unroll
    for (int t = 0; t < 8; t++) s[t] += tk * bf2f((unsigned short)v[t]);
  }
  *reinterpret_cast<float4*>(out + base) = make_float4(s[0], s[1], s[2], s[3]);
  *reinterpret_cast<float4*>(out + base + 4) = make_float4(s[4], s[5], s[6], s[7]);
}

extern "C" void kernel_launch(void* const* d_in, const int* in_sizes, int n_in,
                              void* d_out, int out_size, void* d_ws, size_t ws_size,
                              hipStream_t stream) {
  const float* X    = (const float*)d_in[0];
  const float* EA   = (const float*)d_in[1];
  const float* Ws   = (const float*)d_in[2];
  const float* bs   = (const float*)d_in[3];
  const float* We   = (const float*)d_in[4];
  const float* be   = (const float*)d_in[5];
  const float* temp = (const float*)d_in[6];
  const int*   ei   = (const int*)d_in[7];
  float* out = (float*)d_out;

  size_t off = 0;
  auto alloc = [&](size_t n) { void* p = (char*)d_ws + off; off += (n + 255) & ~(size_t)255; return p; };
  unsigned short* Wt  = (unsigned short*)alloc((size_t)NF * NH * 2);   // 256 KB
  unsigned short* Web = (unsigned short*)alloc((size_t)NH * NC * 2);   // 16 KB
  unsigned short* H   = (unsigned short*)alloc((size_t)NN * NH * 2);   // 51.2 MB = slices 0..7
  unsigned short* x0b = (unsigned short*)alloc((size_t)NN * NC * 2);   // 6.4 MB (gemm2 out)
  unsigned short* xk8 = (unsigned short*)alloc((size_t)NN * NC * 2);   // slice 8
  unsigned short* xk9 = (unsigned short*)alloc((size_t)NN * NC * 2);   // slice 9
  u64*   dc   = (u64*)alloc((size_t)NN * 8);                           // 800 KB
  float* dis  = (float*)alloc((size_t)NN * 4);
  int*   cnt  = (int*)alloc((size_t)NN * 4);
  int*   offs = (int*)alloc((size_t)(NN + 1) * 4);
  int*   cursor = (int*)alloc((size_t)NN * 4);
  int*   bsum = (int*)alloc(98 * 4);
  int*   bofs = (int*)alloc(98 * 4);
  u64*   pk   = (u64*)alloc((size_t)(EE + 8 * NN) * 8);                // 19.2 MB (padded)

  // MLP front-end
  convwb_kernel<<<544, 256, 0, stream>>>(Ws, We, Wt, Web);
  gemm1_kernel<<<1564, 256, 0, stream>>>(X, Wt, bs, H);
  gemm2_kernel<<<1563, 256, 0, stream>>>(H, Web, be, temp, x0b, out);

  // gcn_norm + padded CSR build (by col, so SpMM is atomic-free)
  node_init_kernel<<<391, 256, 0, stream>>>(dc);
  edge_deg_kernel<<<6250, 256, 0, stream>>>(ei, EA, dc);
  dis_kernel<<<391, 256, 0, stream>>>(dc, dis, cnt);
  scan1_kernel<<<98, 256, 0, stream>>>(cnt, bsum);
  scan2_kernel<<<1, 64, 0, stream>>>(bsum, bofs, offs);
  scan3_kernel<<<98, 256, 0, stream>>>(cnt, bofs, offs, cursor);
  fill_kernel<<<6641, 256, 0, stream>>>(ei, EA, dis, cursor, pk);
  pad_kernel<<<391, 256, 0, stream>>>(cursor, offs, pk);

  // K=10 propagation; slice k lives in H (k<8) else xk8/xk9.  NOTE: H is dead
  // after gemm2, so its 51.2 MB is reused as 8 xk slices.
  auto slice = [&](int k) -> unsigned short* {
    return (k < 8) ? H + (size_t)k * NN * NC : (k == 8 ? xk8 : xk9);
  };
  const unsigned short* xin = x0b;
  for (int k = 0; k < KP; k++) {
    spmm_kernel<<<3125, 256, 0, stream>>>(offs, pk, xin, slice(k));
    xin = slice(k);
  }
  wsum_kernel<<<1563, 256, 0, stream>>>(H, xk8, xk9, out, temp);
}

// Round 13
// 537.560 us; speedup vs baseline: 3.9342x; 1.0032x over previous
//
#include <hip/hip_runtime.h>

typedef __attribute__((ext_vector_type(8))) short short8;
typedef __attribute__((ext_vector_type(4))) float f32x4;
typedef unsigned long long u64;

constexpr int NN = 100000;
constexpr int EE = 1600000;
constexpr int NF = 512;
constexpr int NH = 256;
constexpr int NC = 32;
constexpr int KP = 10;

__device__ __forceinline__ unsigned short f2bf(float f) {
  unsigned int u = __float_as_uint(f);
  u += 0x7FFFu + ((u >> 16) & 1u);   // round-to-nearest-even
  return (unsigned short)(u >> 16);
}
__device__ __forceinline__ float bf2f(unsigned short s) {
  return __uint_as_float(((unsigned int)s) << 16);
}
// pad to 8: whole number of 8-batches in spmm, ~18% less pad waste than 16
__device__ __forceinline__ int padc(int c) { return (c + 7) & ~7; }

__device__ __forceinline__ short8 cvt8(float4 a0, float4 a1) {
  union { unsigned int u[4]; short8 s; } r;
  asm("v_cvt_pk_bf16_f32 %0, %1, %2" : "=v"(r.u[0]) : "v"(a0.x), "v"(a0.y));
  asm("v_cvt_pk_bf16_f32 %0, %1, %2" : "=v"(r.u[1]) : "v"(a0.z), "v"(a0.w));
  asm("v_cvt_pk_bf16_f32 %0, %1, %2" : "=v"(r.u[2]) : "v"(a1.x), "v"(a1.y));
  asm("v_cvt_pk_bf16_f32 %0, %1, %2" : "=v"(r.u[3]) : "v"(a1.z), "v"(a1.w));
  return r.s;
}

// Barrier with LDS-only drain: keeps global loads (into registers) in flight
// across the barrier — avoids the compiler's vmcnt(0) drain of __syncthreads.
__device__ __forceinline__ void block_sync_lds() {
  asm volatile("s_waitcnt lgkmcnt(0)" ::: "memory");
  __builtin_amdgcn_s_barrier();
}

// ---- weight conversion: Wt[col][k]=bf(Ws[k][col]); Web[col][k]=bf(We[k][col])
__global__ void convwb_kernel(const float* __restrict__ Ws, const float* __restrict__ We,
                              unsigned short* __restrict__ Wt, unsigned short* __restrict__ Web) {
  int idx = blockIdx.x * 256 + threadIdx.x;      // 544*256 = 139264
  if (idx < 131072) {
    int col = idx >> 9, k = idx & 511;
    Wt[idx] = f2bf(Ws[(size_t)k * NH + col]);
  } else {
    int j = idx - 131072;
    int col = j >> 8, k = j & 255;
    Web[j] = f2bf(We[(size_t)k * NC + col]);
  }
}

// ---- GEMM1+GEMM2 fused -----------------------------------------------------
// h = relu(X[100000,512] @ W[512,256] + bs); h2 = relu(h @ We + be);
// x0b = bf16(h2); out = temp[0]*h2.   H is NEVER materialized to HBM.
// Tile 64 rows x 256 cols (full NH), 4 waves (1x4), wave tile 64x64, BK=32,
// PAD=36, depth-3 reg ring, lgkm-only barriers (R3 skeleton, verified).
// Epilogue: 2 col-half passes through an LDS tile (overlays dead B staging)
// feeding the 256x32 MFMA that was gemm2 — numerically identical path.
__global__ __launch_bounds__(256, 3) void gemm1_kernel(
    const float* __restrict__ X, const unsigned short* __restrict__ Wt,
    const float* __restrict__ bias, const unsigned short* __restrict__ Web,
    const float* __restrict__ be, const float* __restrict__ temp,
    unsigned short* __restrict__ x0b, float* __restrict__ out) {
  constexpr int PAD = 36;
  __shared__ __align__(16) unsigned short Asm[2][64 * PAD];    //  9.2 KB
  __shared__ __align__(16) unsigned short Bsm[2][256 * PAD];   // 36.9 KB
  const int tid = threadIdx.x;
  const int lane = tid & 63;
  const int w = tid >> 6;                    // wave = col strip (1x4 grid)
  const int l15 = lane & 15, kq = lane >> 4;
  const int m0 = blockIdx.x * 64;            // 1563 blocks: 64*1563 >= NN

  // A staging: 4 threads/row (8 floats each), 64 rows
  const int arl = tid >> 2, aq = tid & 3;
  int ar = m0 + arl; if (ar >= NN) ar = NN - 1;
  const float* aptr = X + (size_t)ar * NF + aq * 8;
  const int awr = arl * PAD + aq * 8;
  // B staging: 1 thread/col, 32 ushorts (full 32-k column per phase)
  const unsigned short* bptr = Wt + (size_t)tid * NF;
  const int bwr = tid * PAD;

  f32x4 acc[4][4];
#pragma unroll
  for (int m = 0; m < 4; m++)
#pragma unroll
    for (int n = 0; n < 4; n++) acc[m][n] = (f32x4)0.0f;

  float4 ra[3][2]; short8 rb[3][4];          // depth-3 prefetch ring

#define LOADR(ks, j) do { \
    ra[j][0] = *reinterpret_cast<const float4*>(aptr + (ks) * 32); \
    ra[j][1] = *reinterpret_cast<const float4*>(aptr + (ks) * 32 + 4); \
    rb[j][0] = *reinterpret_cast<const short8*>(bptr + (ks) * 32); \
    rb[j][1] = *reinterpret_cast<const short8*>(bptr + (ks) * 32 + 8); \
    rb[j][2] = *reinterpret_cast<const short8*>(bptr + (ks) * 32 + 16); \
    rb[j][3] = *reinterpret_cast<const short8*>(bptr + (ks) * 32 + 24); \
  } while (0)

#define STAGE(b, j) do { \
    *reinterpret_cast<short8*>(&Asm[b][awr]) = cvt8(ra[j][0], ra[j][1]); \
    *reinterpret_cast<short8*>(&Bsm[b][bwr]) = rb[j][0]; \
    *reinterpret_cast<short8*>(&Bsm[b][bwr + 8]) = rb[j][1]; \
    *reinterpret_cast<short8*>(&Bsm[b][bwr + 16]) = rb[j][2]; \
    *reinterpret_cast<short8*>(&Bsm[b][bwr + 24]) = rb[j][3]; \
  } while (0)

#define COMPUTE(b) do { \
    short8 af[4], bfr[4]; \
    _Pragma("unroll") \
    for (int mi = 0; mi < 4; mi++) \
      af[mi] = *reinterpret_cast<const short8*>(&Asm[b][(mi * 16 + l15) * PAD + kq * 8]); \
    _Pragma("unroll") \
    for (int ni = 0; ni < 4; ni++) \
      bfr[ni] = *reinterpret_cast<const short8*>(&Bsm[b][(w * 64 + ni * 16 + l15) * PAD + kq * 8]); \
    _Pragma("unroll") \
    for (int mi = 0; mi < 4; mi++) \
      _Pragma("unroll") \
      for (int ni = 0; ni < 4; ni++) \
        acc[mi][ni] = __builtin_amdgcn_mfma_f32_16x16x32_bf16(af[mi], bfr[ni], acc[mi][ni], 0, 0, 0); \
  } while (0)

  LOADR(0, 0);
  LOADR(1, 1);
  LOADR(2, 2);
  STAGE(0, 0);
  block_sync_lds();

#pragma unroll
  for (int p = 0; p < 16; p++) {
    if (p + 3 < 16) LOADR(p + 3, (p + 3) % 3);
    COMPUTE(p & 1);
    if (p + 1 < 16) STAGE((p + 1) & 1, (p + 1) % 3);
    block_sync_lds();
  }
#undef LOADR
#undef STAGE
#undef COMPUTE

  // ---- fused gemm2 epilogue.  C/D layout: col=lane&15, row=(lane>>4)*4+i --
  // Ht overlays Bsm (dead after main loop): 64 x 136 bf16 (pad-> b128 reads
  // hit 2-way banks = free).  2 passes over col halves; acc2 accumulates K.
  unsigned short* Ht = (unsigned short*)Bsm;
  f32x4 acc2[2];
  acc2[0] = (f32x4)0.0f; acc2[1] = (f32x4)0.0f;
  const unsigned short* wrow = Web + (size_t)l15 * 256 + kq * 8;
#pragma unroll
  for (int p2 = 0; p2 < 2; p2++) {
    block_sync_lds();
    if ((w >> 1) == p2) {                    // waves 2*p2, 2*p2+1 write
#pragma unroll
      for (int ni = 0; ni < 4; ni++) {
        const int colg = w * 64 + ni * 16 + l15;
        const float bsv = bias[colg];
        const int cl = colg - p2 * 128;
#pragma unroll
        for (int mi = 0; mi < 4; mi++)
#pragma unroll
          for (int i = 0; i < 4; i++) {
            const int row = mi * 16 + kq * 4 + i;
            const float v = acc[mi][ni][i] + bsv;
            Ht[row * 136 + cl] = f2bf(v > 0.f ? v : 0.f);
          }
      }
    }
    block_sync_lds();
    const unsigned short* hr = Ht + (size_t)(w * 16 + l15) * 136 + kq * 8;
#pragma unroll
    for (int ks = 0; ks < 4; ks++) {
      short8 a  = *reinterpret_cast<const short8*>(hr + ks * 32);
      short8 b0 = *reinterpret_cast<const short8*>(wrow + p2 * 128 + ks * 32);
      short8 b1 = *reinterpret_cast<const short8*>(wrow + 16 * 256 + p2 * 128 + ks * 32);
      acc2[0] = __builtin_amdgcn_mfma_f32_16x16x32_bf16(a, b0, acc2[0], 0, 0, 0);
      acc2[1] = __builtin_amdgcn_mfma_f32_16x16x32_bf16(a, b1, acc2[1], 0, 0, 0);
    }
  }
  const float t0 = temp[0];
#pragma unroll
  for (int nt = 0; nt < 2; nt++) {
    const int col = nt * 16 + l15;
    const float bv = be[col];
#pragma unroll
    for (int i = 0; i < 4; i++) {
      const int row = m0 + w * 16 + kq * 4 + i;
      if (row < NN) {
        float v = acc2[nt][i] + bv;
        v = v > 0.f ? v : 0.f;
        x0b[(size_t)row * NC + col] = f2bf(v);
        out[(size_t)row * NC + col] = t0 * v;
      }
    }
  }
}

// ---- graph normalization + CSR build ---------------------------------------
// dc[i]: bits[63:44] = count, bits[43:0] = fixed-point deg (scale 2^32)
__global__ void node_init_kernel(u64* dc) {
  int i = blockIdx.x * 256 + threadIdx.x;
  if (i < NN) dc[i] = (1ULL << 44) | (1ULL << 32);   // self-loop: cnt=1, deg=1.0
}

__global__ void edge_deg_kernel(const int* __restrict__ ei, const float* __restrict__ ew,
                                u64* dc) {
  int e = blockIdx.x * 256 + threadIdx.x;
  if (e < EE) {
    int col = ei[EE + e];
    u64 v = (1ULL << 44) | (u64)((double)ew[e] * 4294967296.0);
    atomicAdd(&dc[col], v);
  }
}

__global__ void dis_kernel(const u64* __restrict__ dc, float* __restrict__ dis,
                           int* __restrict__ cnt) {
  int i = blockIdx.x * 256 + threadIdx.x;
  if (i < NN) {
    u64 v = dc[i];
    cnt[i] = (int)(v >> 44);
    float deg = (float)((double)(v & 0xFFFFFFFFFFFULL) * (1.0 / 4294967296.0));
    dis[i] = rsqrtf(deg);
  }
}

// scans use PADDED counts (mult of 8) so every CSR list is a whole number of
// 8-batches in spmm (no serial remainder tails).
__global__ void scan1_kernel(const int* __restrict__ cnt, int* bsum) {
  __shared__ int ws[4];
  const int tid = threadIdx.x;
  int base = blockIdx.x * 1024 + tid * 4;
  int s = 0;
#pragma unroll
  for (int j = 0; j < 4; j++) { int i = base + j; if (i < NN) s += padc(cnt[i]); }
  for (int off = 32; off > 0; off >>= 1) s += __shfl_down(s, off);
  if ((tid & 63) == 0) ws[tid >> 6] = s;
  __syncthreads();
  if (tid == 0) bsum[blockIdx.x] = ws[0] + ws[1] + ws[2] + ws[3];
}

__global__ void scan2_kernel(const int* __restrict__ bsum, int* bofs, int* offs) {
  if (threadIdx.x == 0) {
    int run = 0;
    for (int i = 0; i < 98; i++) { bofs[i] = run; run += bsum[i]; }
    offs[NN] = run;
  }
}

__global__ void scan3_kernel(const int* __restrict__ cnt, const int* __restrict__ bofs,
                             int* offs, int* cursor) {
  __shared__ int wsum[4];
  const int tid = threadIdx.x;
  const int lane = tid & 63, wv = tid >> 6;
  int base = blockIdx.x * 1024 + tid * 4;
  int v[4]; int s = 0;
#pragma unroll
  for (int j = 0; j < 4; j++) { int i = base + j; v[j] = (i < NN) ? padc(cnt[i]) : 0; s += v[j]; }
  int incl = s;
  for (int off = 1; off < 64; off <<= 1) {
    int t = __shfl_up(incl, off);
    if (lane >= off) incl += t;
  }
  if (lane == 63) wsum[wv] = incl;
  __syncthreads();
  int woff = bofs[blockIdx.x];
  for (int w = 0; w < wv; w++) woff += wsum[w];
  int excl = woff + incl - s;
#pragma unroll
  for (int j = 0; j < 4; j++) {
    int i = base + j;
    if (i < NN) { offs[i] = excl; cursor[i] = excl; }
    excl += v[j];
  }
}

// pk[slot]: low 32 = row index, high 32 = fp32 weight bits
__global__ void fill_kernel(const int* __restrict__ ei, const float* __restrict__ ew,
                            const float* __restrict__ dis, int* cursor,
                            u64* __restrict__ pk) {
  int t = blockIdx.x * 256 + threadIdx.x;
  if (t < EE) {
    int r = ei[t], c = ei[EE + t];
    int slot = atomicAdd(&cursor[c], 1);
    unsigned int wb = __float_as_uint(dis[r] * ew[t] * dis[c]);
    pk[slot] = (u64)(unsigned int)r | ((u64)wb << 32);
  } else if (t < EE + NN) {
    int i = t - EE;
    int slot = atomicAdd(&cursor[i], 1);
    float d = dis[i];
    unsigned int wb = __float_as_uint(d * d);
    pk[slot] = (u64)(unsigned int)i | ((u64)wb << 32);
  }
}

// zero-fill the padding gap [cursor[i], offs[i+1]) with row=0, weight=0
__global__ void pad_kernel(const int* __restrict__ cursor, const int* __restrict__ offs,
                           u64* __restrict__ pk) {
  int i = blockIdx.x * 256 + threadIdx.x;
  if (i < NN) {
    int j = cursor[i], e = offs[i + 1];
    for (; j < e; j++) pk[j] = 0;
  }
}

// ---- SpMM (bf16 xk): xout = A*xin ------------------------------------------
// R9 shape (verified fastest): 8 lanes/node, 8B gathers, batch 8, 3125 blocks.
// pk loads paired as 16B (8-aligned offsets keep alignment).
__global__ __launch_bounds__(256) void spmm_kernel(
    const int* __restrict__ offs, const u64* __restrict__ pk,
    const unsigned short* __restrict__ xin, unsigned short* __restrict__ xout) {
  const int tid = threadIdx.x;
  const int node = blockIdx.x * 32 + (tid >> 3);   // 3125*32 = 100000 exact
  const int fq = (tid & 7) * 4;                    // feature quad base
  const int s = offs[node], e = offs[node + 1];
  float a0 = 0.f, a1 = 0.f, a2 = 0.f, a3 = 0.f;
  for (int j = s; j < e; j += 8) {
    ulonglong2 p01 = *reinterpret_cast<const ulonglong2*>(pk + j);
    ulonglong2 p23 = *reinterpret_cast<const ulonglong2*>(pk + j + 2);
    ulonglong2 p45 = *reinterpret_cast<const ulonglong2*>(pk + j + 4);
    ulonglong2 p67 = *reinterpret_cast<const ulonglong2*>(pk + j + 6);
    const u64 p[8] = {p01.x, p01.y, p23.x, p23.y, p45.x, p45.y, p67.x, p67.y};
    u64 q[8];
#pragma unroll
    for (int i = 0; i < 8; i++)
      q[i] = *reinterpret_cast<const u64*>(xin + (size_t)(unsigned int)p[i] * NC + fq);
#pragma unroll
    for (int i = 0; i < 8; i++) {
      const float w = __uint_as_float((unsigned int)(p[i] >> 32));
      a0 += w * bf2f((unsigned short)(q[i]));
      a1 += w * bf2f((unsigned short)(q[i] >> 16));
      a2 += w * bf2f((unsigned short)(q[i] >> 32));
      a3 += w * bf2f((unsigned short)(q[i] >> 48));
    }
  }
  // pack 4 bf16 (RNE via cvt_pk) and store 8B
  unsigned int lo, hi;
  asm("v_cvt_pk_bf16_f32 %0, %1, %2" : "=v"(lo) : "v"(a0), "v"(a1));
  asm("v_cvt_pk_bf16_f32 %0, %1, %2" : "=v"(hi) : "v"(a2), "v"(a3));
  *reinterpret_cast<u64*>(xout + (size_t)node * NC + fq) =
      (u64)lo | ((u64)hi << 32);
}

// ---- final weighted sum: out += sum_k temp[k+1] * xk_k (8 feats/thread) ----
__global__ __launch_bounds__(256) void wsum_kernel(
    const unsigned short* __restrict__ S07,   // slices 0..7 (H region)
    const unsigned short* __restrict__ S8, const unsigned short* __restrict__ S9,
    float* __restrict__ out, const float* __restrict__ temp) {
  int t8 = blockIdx.x * 256 + threadIdx.x;    // 1563*256 = 400128 >= 400000
  if (t8 >= NN * NC / 8) return;
  const size_t base = (size_t)t8 * 8;
  float s[8];
  float4 o0 = *reinterpret_cast<const float4*>(out + base);
  float4 o1 = *reinterpret_cast<const float4*>(out + base + 4);
  s[0] = o0.x; s[1] = o0.y; s[2] = o0.z; s[3] = o0.w;
  s[4] = o1.x; s[5] = o1.y; s[6] = o1.z; s[7] = o1.w;
#pragma unroll
  for (int k = 0; k < 8; k++) {
    const float tk = temp[k + 1];
    short8 v = *reinterpret_cast<const short8*>(S07 + (size_t)k * NN * NC + base);
#pragma unroll
    for (int t = 0; t < 8; t++) s[t] += tk * bf2f((unsigned short)v[t]);
  }
  {
    const float tk = temp[9];
    short8 v = *reinterpret_cast<const short8*>(S8 + base);
#pragma unroll
    for (int t = 0; t < 8; t++) s[t] += tk * bf2f((unsigned short)v[t]);
  }
  {
    const float tk = temp[10];
    short8 v = *reinterpret_cast<const short8*>(S9 + base);
#pragma unroll
    for (int t = 0; t < 8; t++) s[t] += tk * bf2f((unsigned short)v[t]);
  }
  *reinterpret_cast<float4*>(out + base) = make_float4(s[0], s[1], s[2], s[3]);
  *reinterpret_cast<float4*>(out + base + 4) = make_float4(s[4], s[5], s[6], s[7]);
}

extern "C" void kernel_launch(void* const* d_in, const int* in_sizes, int n_in,
                              void* d_out, int out_size, void* d_ws, size_t ws_size,
                              hipStream_t stream) {
  const float* X    = (const float*)d_in[0];
  const float* EA   = (const float*)d_in[1];
  const float* Ws   = (const float*)d_in[2];
  const float* bs   = (const float*)d_in[3];
  const float* We   = (const float*)d_in[4];
  const float* be   = (const float*)d_in[5];
  const float* temp = (const float*)d_in[6];
  const int*   ei   = (const int*)d_in[7];
  float* out = (float*)d_out;

  size_t off = 0;
  auto alloc = [&](size_t n) { void* p = (char*)d_ws + off; off += (n + 255) & ~(size_t)255; return p; };
  unsigned short* Wt  = (unsigned short*)alloc((size_t)NF * NH * 2);   // 256 KB
  unsigned short* Web = (unsigned short*)alloc((size_t)NH * NC * 2);   // 16 KB
  unsigned short* SL  = (unsigned short*)alloc((size_t)NN * NH * 2);   // 51.2 MB = xk slices 0..7
  unsigned short* x0b = (unsigned short*)alloc((size_t)NN * NC * 2);   // 6.4 MB (fused gemm out)
  unsigned short* xk8 = (unsigned short*)alloc((size_t)NN * NC * 2);   // slice 8
  unsigned short* xk9 = (unsigned short*)alloc((size_t)NN * NC * 2);   // slice 9
  u64*   dc   = (u64*)alloc((size_t)NN * 8);                           // 800 KB
  float* dis  = (float*)alloc((size_t)NN * 4);
  int*   cnt  = (int*)alloc((size_t)NN * 4);
  int*   offs = (int*)alloc((size_t)(NN + 1) * 4);
  int*   cursor = (int*)alloc((size_t)NN * 4);
  int*   bsum = (int*)alloc(98 * 4);
  int*   bofs = (int*)alloc(98 * 4);
  u64*   pk   = (u64*)alloc((size_t)(EE + 8 * NN) * 8);                // 19.2 MB (padded)

  // MLP front-end (gemm1+gemm2 fused; H never hits HBM)
  convwb_kernel<<<544, 256, 0, stream>>>(Ws, We, Wt, Web);
  gemm1_kernel<<<1563, 256, 0, stream>>>(X, Wt, bs, Web, be, temp, x0b, out);

  // gcn_norm + padded CSR build (by col, so SpMM is atomic-free)
  node_init_kernel<<<391, 256, 0, stream>>>(dc);
  edge_deg_kernel<<<6250, 256, 0, stream>>>(ei, EA, dc);
  dis_kernel<<<391, 256, 0, stream>>>(dc, dis, cnt);
  scan1_kernel<<<98, 256, 0, stream>>>(cnt, bsum);
  scan2_kernel<<<1, 64, 0, stream>>>(bsum, bofs, offs);
  scan3_kernel<<<98, 256, 0, stream>>>(cnt, bofs, offs, cursor);
  fill_kernel<<<6641, 256, 0, stream>>>(ei, EA, dis, cursor, pk);
  pad_kernel<<<391, 256, 0, stream>>>(cursor, offs, pk);

  // K=10 propagation; slice k lives in SL (k<8) else xk8/xk9.
  auto slice = [&](int k) -> unsigned short* {
    return (k < 8) ? SL + (size_t)k * NN * NC : (k == 8 ? xk8 : xk9);
  };
  const unsigned short* xin = x0b;
  for (int k = 0; k < KP; k++) {
    spmm_kernel<<<3125, 256, 0, stream>>>(offs, pk, xin, slice(k));
    xin = slice(k);
  }
  wsum_kernel<<<1563, 256, 0, stream>>>(SL, xk8, xk9, out, temp);
}

// Round 14
// 534.642 us; speedup vs baseline: 3.9557x; 1.0055x over previous
//
#include <hip/hip_runtime.h>

typedef __attribute__((ext_vector_type(8))) short short8;
typedef __attribute__((ext_vector_type(4))) float f32x4;
typedef unsigned long long u64;

constexpr int NN = 100000;
constexpr int EE = 1600000;
constexpr int NF = 512;
constexpr int NH = 256;
constexpr int NC = 32;
constexpr int KP = 10;
constexpr int PKN = EE + 8 * NN;   // padded pk entries

__device__ __forceinline__ unsigned short f2bf(float f) {
  unsigned int u = __float_as_uint(f);
  u += 0x7FFFu + ((u >> 16) & 1u);   // round-to-nearest-even
  return (unsigned short)(u >> 16);
}
__device__ __forceinline__ float bf2f(unsigned short s) {
  return __uint_as_float(((unsigned int)s) << 16);
}
// pad to 8: whole number of 8-batches in spmm
__device__ __forceinline__ int padc(int c) { return (c + 7) & ~7; }

__device__ __forceinline__ short8 cvt8(float4 a0, float4 a1) {
  union { unsigned int u[4]; short8 s; } r;
  asm("v_cvt_pk_bf16_f32 %0, %1, %2" : "=v"(r.u[0]) : "v"(a0.x), "v"(a0.y));
  asm("v_cvt_pk_bf16_f32 %0, %1, %2" : "=v"(r.u[1]) : "v"(a0.z), "v"(a0.w));
  asm("v_cvt_pk_bf16_f32 %0, %1, %2" : "=v"(r.u[2]) : "v"(a1.x), "v"(a1.y));
  asm("v_cvt_pk_bf16_f32 %0, %1, %2" : "=v"(r.u[3]) : "v"(a1.z), "v"(a1.w));
  return r.s;
}

// Barrier with LDS-only drain: keeps global loads (into registers) in flight
// across the barrier — avoids the compiler's vmcnt(0) drain of __syncthreads.
__device__ __forceinline__ void block_sync_lds() {
  asm volatile("s_waitcnt lgkmcnt(0)" ::: "memory");
  __builtin_amdgcn_s_barrier();
}

// ---- weight conversion (coalesced LDS transpose) ---------------------------
// Wt[col][k]=bf(Ws[k][col]) via 64x64 tiles; Web[col][k]=bf(We[k][col]).
__global__ void convwb_kernel(const float* __restrict__ Ws, const float* __restrict__ We,
                              unsigned short* __restrict__ Wt, unsigned short* __restrict__ Web) {
  if (blockIdx.x < 32) {
    __shared__ float tile[64][65];
    const int k0 = (blockIdx.x >> 2) * 64;   // 8 k-tiles
    const int c0 = (blockIdx.x & 3) * 64;    // 4 col-tiles
    const int t = threadIdx.x;
    const int g = t >> 6, l = t & 63;
#pragma unroll
    for (int j = 0; j < 16; j++) {
      const int row = g * 16 + j;
      tile[row][l] = Ws[(size_t)(k0 + row) * NH + c0 + l];
    }
    __syncthreads();
    const int col = t >> 2, ks = (t & 3) * 16;
    union { unsigned short us[16]; short8 s8[2]; } st;
#pragma unroll
    for (int i = 0; i < 16; i++) st.us[i] = f2bf(tile[ks + i][col]);
    unsigned short* dst = Wt + (size_t)(c0 + col) * NF + k0 + ks;
    *reinterpret_cast<short8*>(dst) = st.s8[0];
    *reinterpret_cast<short8*>(dst + 8) = st.s8[1];
  } else {
    const int t = threadIdx.x;               // 256 thr x 32 = 8192 elems
    const int col = t & 31, kb = (t >> 5) * 32;
#pragma unroll
    for (int i = 0; i < 32; i++)
      Web[(size_t)col * 256 + kb + i] = f2bf(We[(size_t)(kb + i) * NC + col]);
  }
}

// ---- GEMM1+GEMM2 fused (R13, verified) -------------------------------------
__global__ __launch_bounds__(256, 3) void gemm1_kernel(
    const float* __restrict__ X, const unsigned short* __restrict__ Wt,
    const float* __restrict__ bias, const unsigned short* __restrict__ Web,
    const float* __restrict__ be, const float* __restrict__ temp,
    unsigned short* __restrict__ x0b, float* __restrict__ out) {
  constexpr int PAD = 36;
  __shared__ __align__(16) unsigned short Asm[2][64 * PAD];    //  9.2 KB
  __shared__ __align__(16) unsigned short Bsm[2][256 * PAD];   // 36.9 KB
  const int tid = threadIdx.x;
  const int lane = tid & 63;
  const int w = tid >> 6;                    // wave = col strip (1x4 grid)
  const int l15 = lane & 15, kq = lane >> 4;
  const int m0 = blockIdx.x * 64;            // 1563 blocks: 64*1563 >= NN

  const int arl = tid >> 2, aq = tid & 3;
  int ar = m0 + arl; if (ar >= NN) ar = NN - 1;
  const float* aptr = X + (size_t)ar * NF + aq * 8;
  const int awr = arl * PAD + aq * 8;
  const unsigned short* bptr = Wt + (size_t)tid * NF;
  const int bwr = tid * PAD;

  f32x4 acc[4][4];
#pragma unroll
  for (int m = 0; m < 4; m++)
#pragma unroll
    for (int n = 0; n < 4; n++) acc[m][n] = (f32x4)0.0f;

  float4 ra[3][2]; short8 rb[3][4];          // depth-3 prefetch ring

#define LOADR(ks, j) do { \
    ra[j][0] = *reinterpret_cast<const float4*>(aptr + (ks) * 32); \
    ra[j][1] = *reinterpret_cast<const float4*>(aptr + (ks) * 32 + 4); \
    rb[j][0] = *reinterpret_cast<const short8*>(bptr + (ks) * 32); \
    rb[j][1] = *reinterpret_cast<const short8*>(bptr + (ks) * 32 + 8); \
    rb[j][2] = *reinterpret_cast<const short8*>(bptr + (ks) * 32 + 16); \
    rb[j][3] = *reinterpret_cast<const short8*>(bptr + (ks) * 32 + 24); \
  } while (0)

#define STAGE(b, j) do { \
    *reinterpret_cast<short8*>(&Asm[b][awr]) = cvt8(ra[j][0], ra[j][1]); \
    *reinterpret_cast<short8*>(&Bsm[b][bwr]) = rb[j][0]; \
    *reinterpret_cast<short8*>(&Bsm[b][bwr + 8]) = rb[j][1]; \
    *reinterpret_cast<short8*>(&Bsm[b][bwr + 16]) = rb[j][2]; \
    *reinterpret_cast<short8*>(&Bsm[b][bwr + 24]) = rb[j][3]; \
  } while (0)

#define COMPUTE(b) do { \
    short8 af[4], bfr[4]; \
    _Pragma("unroll") \
    for (int mi = 0; mi < 4; mi++) \
      af[mi] = *reinterpret_cast<const short8*>(&Asm[b][(mi * 16 + l15) * PAD + kq * 8]); \
    _Pragma("unroll") \
    for (int ni = 0; ni < 4; ni++) \
      bfr[ni] = *reinterpret_cast<const short8*>(&Bsm[b][(w * 64 + ni * 16 + l15) * PAD + kq * 8]); \
    _Pragma("unroll") \
    for (int mi = 0; mi < 4; mi++) \
      _Pragma("unroll") \
      for (int ni = 0; ni < 4; ni++) \
        acc[mi][ni] = __builtin_amdgcn_mfma_f32_16x16x32_bf16(af[mi], bfr[ni], acc[mi][ni], 0, 0, 0); \
  } while (0)

  LOADR(0, 0);
  LOADR(1, 1);
  LOADR(2, 2);
  STAGE(0, 0);
  block_sync_lds();

#pragma unroll
  for (int p = 0; p < 16; p++) {
    if (p + 3 < 16) LOADR(p + 3, (p + 3) % 3);
    COMPUTE(p & 1);
    if (p + 1 < 16) STAGE((p + 1) & 1, (p + 1) % 3);
    block_sync_lds();
  }
#undef LOADR
#undef STAGE
#undef COMPUTE

  // ---- fused gemm2 epilogue (verified R13 path) ----------------------------
  unsigned short* Ht = (unsigned short*)Bsm;
  f32x4 acc2[2];
  acc2[0] = (f32x4)0.0f; acc2[1] = (f32x4)0.0f;
  const unsigned short* wrow = Web + (size_t)l15 * 256 + kq * 8;
#pragma unroll
  for (int p2 = 0; p2 < 2; p2++) {
    block_sync_lds();
    if ((w >> 1) == p2) {
#pragma unroll
      for (int ni = 0; ni < 4; ni++) {
        const int colg = w * 64 + ni * 16 + l15;
        const float bsv = bias[colg];
        const int cl = colg - p2 * 128;
#pragma unroll
        for (int mi = 0; mi < 4; mi++)
#pragma unroll
          for (int i = 0; i < 4; i++) {
            const int row = mi * 16 + kq * 4 + i;
            const float v = acc[mi][ni][i] + bsv;
            Ht[row * 136 + cl] = f2bf(v > 0.f ? v : 0.f);
          }
      }
    }
    block_sync_lds();
    const unsigned short* hr = Ht + (size_t)(w * 16 + l15) * 136 + kq * 8;
#pragma unroll
    for (int ks = 0; ks < 4; ks++) {
      short8 a  = *reinterpret_cast<const short8*>(hr + ks * 32);
      short8 b0 = *reinterpret_cast<const short8*>(wrow + p2 * 128 + ks * 32);
      short8 b1 = *reinterpret_cast<const short8*>(wrow + 16 * 256 + p2 * 128 + ks * 32);
      acc2[0] = __builtin_amdgcn_mfma_f32_16x16x32_bf16(a, b0, acc2[0], 0, 0, 0);
      acc2[1] = __builtin_amdgcn_mfma_f32_16x16x32_bf16(a, b1, acc2[1], 0, 0, 0);
    }
  }
  const float t0 = temp[0];
#pragma unroll
  for (int nt = 0; nt < 2; nt++) {
    const int col = nt * 16 + l15;
    const float bv = be[col];
#pragma unroll
    for (int i = 0; i < 4; i++) {
      const int row = m0 + w * 16 + kq * 4 + i;
      if (row < NN) {
        float v = acc2[nt][i] + bv;
        v = v > 0.f ? v : 0.f;
        x0b[(size_t)row * NC + col] = f2bf(v);
        out[(size_t)row * NC + col] = t0 * v;
      }
    }
  }
}

// ---- graph normalization + CSR build ---------------------------------------
// dc[i]: bits[63:44] = count, bits[43:0] = fixed-point deg (scale 2^32)
// Also pre-zeros the padded pk buffer (replaces pad_kernel: fill only writes
// real entries; padding gaps stay zero = row 0, weight 0 -> harmless).
__global__ void node_init_kernel(u64* dc, u64* pk) {
  int i = blockIdx.x * 256 + threadIdx.x;
  if (i < NN) dc[i] = (1ULL << 44) | (1ULL << 32);   // self-loop: cnt=1, deg=1.0
  for (int j = i; j < PKN; j += 391 * 256) pk[j] = 0;
}

__global__ void edge_deg_kernel(const int* __restrict__ ei, const float* __restrict__ ew,
                                u64* dc) {
  int e = blockIdx.x * 256 + threadIdx.x;
  if (e < EE) {
    int col = ei[EE + e];
    u64 v = (1ULL << 44) | (u64)((double)ew[e] * 4294967296.0);
    atomicAdd(&dc[col], v);
  }
}

__global__ void dis_kernel(const u64* __restrict__ dc, float* __restrict__ dis,
                           int* __restrict__ cnt) {
  int i = blockIdx.x * 256 + threadIdx.x;
  if (i < NN) {
    u64 v = dc[i];
    cnt[i] = (int)(v >> 44);
    float deg = (float)((double)(v & 0xFFFFFFFFFFFULL) * (1.0 / 4294967296.0));
    dis[i] = rsqrtf(deg);
  }
}

// scans use PADDED counts (mult of 8) so every CSR list is a whole number of
// 8-batches in spmm (no serial remainder tails).
__global__ void scan1_kernel(const int* __restrict__ cnt, int* bsum) {
  __shared__ int ws[4];
  const int tid = threadIdx.x;
  int base = blockIdx.x * 1024 + tid * 4;
  int s = 0;
#pragma unroll
  for (int j = 0; j < 4; j++) { int i = base + j; if (i < NN) s += padc(cnt[i]); }
  for (int off = 32; off > 0; off >>= 1) s += __shfl_down(s, off);
  if ((tid & 63) == 0) ws[tid >> 6] = s;
  __syncthreads();
  if (tid == 0) bsum[blockIdx.x] = ws[0] + ws[1] + ws[2] + ws[3];
}

// scan3 with inlined scan2: each block redundantly prefix-sums the 98 block
// sums (98 serial adds by thread 0 — trivial); block 0 also writes offs[NN].
__global__ void scan3_kernel(const int* __restrict__ cnt, const int* __restrict__ bsum,
                             int* offs, int* cursor) {
  __shared__ int wsum[4];
  __shared__ int bofs_s;
  const int tid = threadIdx.x;
  const int lane = tid & 63, wv = tid >> 6;
  if (tid == 0) {
    int run = 0;
    for (int i = 0; i < (int)blockIdx.x; i++) run += bsum[i];
    bofs_s = run;
    if (blockIdx.x == 0) {
      int tot = 0;
      for (int i = 0; i < 98; i++) tot += bsum[i];
      offs[NN] = tot;
    }
  }
  int base = blockIdx.x * 1024 + tid * 4;
  int v[4]; int s = 0;
#pragma unroll
  for (int j = 0; j < 4; j++) { int i = base + j; v[j] = (i < NN) ? padc(cnt[i]) : 0; s += v[j]; }
  int incl = s;
  for (int off = 1; off < 64; off <<= 1) {
    int t = __shfl_up(incl, off);
    if (lane >= off) incl += t;
  }
  if (lane == 63) wsum[wv] = incl;
  __syncthreads();
  int woff = bofs_s;
  for (int w = 0; w < wv; w++) woff += wsum[w];
  int excl = woff + incl - s;
#pragma unroll
  for (int j = 0; j < 4; j++) {
    int i = base + j;
    if (i < NN) { offs[i] = excl; cursor[i] = excl; }
    excl += v[j];
  }
}

// pk[slot]: low 32 = row index, high 32 = fp32 weight bits
__global__ void fill_kernel(const int* __restrict__ ei, const float* __restrict__ ew,
                            const float* __restrict__ dis, int* cursor,
                            u64* __restrict__ pk) {
  int t = blockIdx.x * 256 + threadIdx.x;
  if (t < EE) {
    int r = ei[t], c = ei[EE + t];
    int slot = atomicAdd(&cursor[c], 1);
    unsigned int wb = __float_as_uint(dis[r] * ew[t] * dis[c]);
    pk[slot] = (u64)(unsigned int)r | ((u64)wb << 32);
  } else if (t < EE + NN) {
    int i = t - EE;
    int slot = atomicAdd(&cursor[i], 1);
    float d = dis[i];
    unsigned int wb = __float_as_uint(d * d);
    pk[slot] = (u64)(unsigned int)i | ((u64)wb << 32);
  }
}

// ---- SpMM (bf16 xk): xout = A*xin (R12 shape, verified fastest) ------------
__global__ __launch_bounds__(256) void spmm_kernel(
    const int* __restrict__ offs, const u64* __restrict__ pk,
    const unsigned short* __restrict__ xin, unsigned short* __restrict__ xout) {
  const int tid = threadIdx.x;
  const int node = blockIdx.x * 32 + (tid >> 3);   // 3125*32 = 100000 exact
  const int fq = (tid & 7) * 4;                    // feature quad base
  const int s = offs[node], e = offs[node + 1];
  float a0 = 0.f, a1 = 0.f, a2 = 0.f, a3 = 0.f;
  for (int j = s; j < e; j += 8) {
    ulonglong2 p01 = *reinterpret_cast<const ulonglong2*>(pk + j);
    ulonglong2 p23 = *reinterpret_cast<const ulonglong2*>(pk + j + 2);
    ulonglong2 p45 = *reinterpret_cast<const ulonglong2*>(pk + j + 4);
    ulonglong2 p67 = *reinterpret_cast<const ulonglong2*>(pk + j + 6);
    const u64 p[8] = {p01.x, p01.y, p23.x, p23.y, p45.x, p45.y, p67.x, p67.y};
    u64 q[8];
#pragma unroll
    for (int i = 0; i < 8; i++)
      q[i] = *reinterpret_cast<const u64*>(xin + (size_t)(unsigned int)p[i] * NC + fq);
#pragma unroll
    for (int i = 0; i < 8; i++) {
      const float w = __uint_as_float((unsigned int)(p[i] >> 32));
      a0 += w * bf2f((unsigned short)(q[i]));
      a1 += w * bf2f((unsigned short)(q[i] >> 16));
      a2 += w * bf2f((unsigned short)(q[i] >> 32));
      a3 += w * bf2f((unsigned short)(q[i] >> 48));
    }
  }
  unsigned int lo, hi;
  asm("v_cvt_pk_bf16_f32 %0, %1, %2" : "=v"(lo) : "v"(a0), "v"(a1));
  asm("v_cvt_pk_bf16_f32 %0, %1, %2" : "=v"(hi) : "v"(a2), "v"(a3));
  *reinterpret_cast<u64*>(xout + (size_t)node * NC + fq) =
      (u64)lo | ((u64)hi << 32);
}

// ---- last SpMM fused with the weighted sum ---------------------------------
// Computes xk_9 in-register (temp[10] term), gathers slices 0..8 (temp[1..9])
// and writes out once.  Saves the xk9 write+read (12.8 MB) and one launch.
__global__ __launch_bounds__(256) void spmm_wsum_kernel(
    const int* __restrict__ offs, const u64* __restrict__ pk,
    const unsigned short* __restrict__ xin,        // = slice 8
    const unsigned short* __restrict__ SL,         // slices 0..7
    float* __restrict__ out, const float* __restrict__ temp) {
  const int tid = threadIdx.x;
  const int node = blockIdx.x * 32 + (tid >> 3);
  const int fq = (tid & 7) * 4;
  const int s = offs[node], e = offs[node + 1];
  float a0 = 0.f, a1 = 0.f, a2 = 0.f, a3 = 0.f;
  for (int j = s; j < e; j += 8) {
    ulonglong2 p01 = *reinterpret_cast<const ulonglong2*>(pk + j);
    ulonglong2 p23 = *reinterpret_cast<const ulonglong2*>(pk + j + 2);
    ulonglong2 p45 = *reinterpret_cast<const ulonglong2*>(pk + j + 4);
    ulonglong2 p67 = *reinterpret_cast<const ulonglong2*>(pk + j + 6);
    const u64 p[8] = {p01.x, p01.y, p23.x, p23.y, p45.x, p45.y, p67.x, p67.y};
    u64 q[8];
#pragma unroll
    for (int i = 0; i < 8; i++)
      q[i] = *reinterpret_cast<const u64*>(xin + (size_t)(unsigned int)p[i] * NC + fq);
#pragma unroll
    for (int i = 0; i < 8; i++) {
      const float w = __uint_as_float((unsigned int)(p[i] >> 32));
      a0 += w * bf2f((unsigned short)(q[i]));
      a1 += w * bf2f((unsigned short)(q[i] >> 16));
      a2 += w * bf2f((unsigned short)(q[i] >> 32));
      a3 += w * bf2f((unsigned short)(q[i] >> 48));
    }
  }
  const size_t ob = (size_t)node * NC + fq;
  float4 o = *reinterpret_cast<const float4*>(out + ob);
  const float t10 = temp[10];
  float r0 = o.x + t10 * a0, r1 = o.y + t10 * a1;
  float r2 = o.z + t10 * a2, r3 = o.w + t10 * a3;
#pragma unroll
  for (int k = 0; k < 8; k++) {
    const float tk = temp[k + 1];
    u64 q = *reinterpret_cast<const u64*>(SL + (size_t)k * NN * NC + ob);
    r0 += tk * bf2f((unsigned short)(q));
    r1 += tk * bf2f((unsigned short)(q >> 16));
    r2 += tk * bf2f((unsigned short)(q >> 32));
    r3 += tk * bf2f((unsigned short)(q >> 48));
  }
  {
    const float tk = temp[9];                      // slice 8 == xin
    u64 q = *reinterpret_cast<const u64*>(xin + ob);
    r0 += tk * bf2f((unsigned short)(q));
    r1 += tk * bf2f((unsigned short)(q >> 16));
    r2 += tk * bf2f((unsigned short)(q >> 32));
    r3 += tk * bf2f((unsigned short)(q >> 48));
  }
  *reinterpret_cast<float4*>(out + ob) = make_float4(r0, r1, r2, r3);
}

extern "C" void kernel_launch(void* const* d_in, const int* in_sizes, int n_in,
                              void* d_out, int out_size, void* d_ws, size_t ws_size,
                              hipStream_t stream) {
  const float* X    = (const float*)d_in[0];
  const float* EA   = (const float*)d_in[1];
  const float* Ws   = (const float*)d_in[2];
  const float* bs   = (const float*)d_in[3];
  const float* We   = (const float*)d_in[4];
  const float* be   = (const float*)d_in[5];
  const float* temp = (const float*)d_in[6];
  const int*   ei   = (const int*)d_in[7];
  float* out = (float*)d_out;

  size_t off = 0;
  auto alloc = [&](size_t n) { void* p = (char*)d_ws + off; off += (n + 255) & ~(size_t)255; return p; };
  unsigned short* Wt  = (unsigned short*)alloc((size_t)NF * NH * 2);   // 256 KB
  unsigned short* Web = (unsigned short*)alloc((size_t)NH * NC * 2);   // 16 KB
  unsigned short* SL  = (unsigned short*)alloc((size_t)NN * NH * 2);   // 51.2 MB = xk slices 0..7
  unsigned short* x0b = (unsigned short*)alloc((size_t)NN * NC * 2);   // 6.4 MB (fused gemm out)
  unsigned short* xk8 = (unsigned short*)alloc((size_t)NN * NC * 2);   // slice 8
  u64*   dc   = (u64*)alloc((size_t)NN * 8);                           // 800 KB
  float* dis  = (float*)alloc((size_t)NN * 4);
  int*   cnt  = (int*)alloc((size_t)NN * 4);
  int*   offs = (int*)alloc((size_t)(NN + 1) * 4);
  int*   cursor = (int*)alloc((size_t)NN * 4);
  int*   bsum = (int*)alloc(98 * 4);
  u64*   pk   = (u64*)alloc((size_t)PKN * 8);                          // 19.2 MB (padded)

  // MLP front-end (gemm1+gemm2 fused; H never hits HBM)
  convwb_kernel<<<33, 256, 0, stream>>>(Ws, We, Wt, Web);
  gemm1_kernel<<<1563, 256, 0, stream>>>(X, Wt, bs, Web, be, temp, x0b, out);

  // gcn_norm + padded CSR build (by col, so SpMM is atomic-free)
  node_init_kernel<<<391, 256, 0, stream>>>(dc, pk);
  edge_deg_kernel<<<6250, 256, 0, stream>>>(ei, EA, dc);
  dis_kernel<<<391, 256, 0, stream>>>(dc, dis, cnt);
  scan1_kernel<<<98, 256, 0, stream>>>(cnt, bsum);
  scan3_kernel<<<98, 256, 0, stream>>>(cnt, bsum, offs, cursor);
  fill_kernel<<<6641, 256, 0, stream>>>(ei, EA, dis, cursor, pk);

  // K=10 propagation; slices 0..7 in SL, slice 8 in xk8; last hop fused w/ sum
  auto slice = [&](int k) -> unsigned short* {
    return (k < 8) ? SL + (size_t)k * NN * NC : xk8;
  };
  const unsigned short* xin = x0b;
  for (int k = 0; k < KP - 1; k++) {
    spmm_kernel<<<3125, 256, 0, stream>>>(offs, pk, xin, slice(k));
    xin = slice(k);
  }
  spmm_wsum_kernel<<<3125, 256, 0, stream>>>(offs, pk, xk8, SL, out, temp);
}

// Round 15
// 504.310 us; speedup vs baseline: 4.1936x; 1.0601x over previous
//
#include <hip/hip_runtime.h>

typedef __attribute__((ext_vector_type(8))) short short8;
typedef __attribute__((ext_vector_type(4))) float f32x4;
typedef unsigned long long u64;

constexpr int NN = 100000;
constexpr int EE = 1600000;
constexpr int NF = 512;
constexpr int NH = 256;
constexpr int NC = 32;
constexpr int KP = 10;
constexpr int PKN = EE + 8 * NN;   // padded pk entries
constexpr int GB = 1563;           // gemm blocks in the fused gemm+deg kernel

__device__ __forceinline__ unsigned short f2bf(float f) {
  unsigned int u = __float_as_uint(f);
  u += 0x7FFFu + ((u >> 16) & 1u);   // round-to-nearest-even
  return (unsigned short)(u >> 16);
}
__device__ __forceinline__ float bf2f(unsigned short s) {
  return __uint_as_float(((unsigned int)s) << 16);
}
// pad to 8: whole number of 8-batches in spmm
__device__ __forceinline__ int padc(int c) { return (c + 7) & ~7; }

__device__ __forceinline__ short8 cvt8(float4 a0, float4 a1) {
  union { unsigned int u[4]; short8 s; } r;
  asm("v_cvt_pk_bf16_f32 %0, %1, %2" : "=v"(r.u[0]) : "v"(a0.x), "v"(a0.y));
  asm("v_cvt_pk_bf16_f32 %0, %1, %2" : "=v"(r.u[1]) : "v"(a0.z), "v"(a0.w));
  asm("v_cvt_pk_bf16_f32 %0, %1, %2" : "=v"(r.u[2]) : "v"(a1.x), "v"(a1.y));
  asm("v_cvt_pk_bf16_f32 %0, %1, %2" : "=v"(r.u[3]) : "v"(a1.z), "v"(a1.w));
  return r.s;
}

// Barrier with LDS-only drain: keeps global loads (into registers) in flight
// across the barrier — avoids the compiler's vmcnt(0) drain of __syncthreads.
__device__ __forceinline__ void block_sync_lds() {
  asm volatile("s_waitcnt lgkmcnt(0)" ::: "memory");
  __builtin_amdgcn_s_barrier();
}

// ---- prep: weight conversion + dc init + pk zero (all independent) ---------
// blocks 0..31: Ws transpose tiles; block 32: Web; blocks 33..423: dc + pk.
__global__ void prep_kernel(const float* __restrict__ Ws, const float* __restrict__ We,
                            unsigned short* __restrict__ Wt, unsigned short* __restrict__ Web,
                            u64* __restrict__ dc, u64* __restrict__ pk) {
  if (blockIdx.x < 32) {
    __shared__ float tile[64][65];
    const int k0 = (blockIdx.x >> 2) * 64;   // 8 k-tiles
    const int c0 = (blockIdx.x & 3) * 64;    // 4 col-tiles
    const int t = threadIdx.x;
    const int g = t >> 6, l = t & 63;
#pragma unroll
    for (int j = 0; j < 16; j++) {
      const int row = g * 16 + j;
      tile[row][l] = Ws[(size_t)(k0 + row) * NH + c0 + l];
    }
    __syncthreads();
    const int col = t >> 2, ks = (t & 3) * 16;
    union { unsigned short us[16]; short8 s8[2]; } st;
#pragma unroll
    for (int i = 0; i < 16; i++) st.us[i] = f2bf(tile[ks + i][col]);
    unsigned short* dst = Wt + (size_t)(c0 + col) * NF + k0 + ks;
    *reinterpret_cast<short8*>(dst) = st.s8[0];
    *reinterpret_cast<short8*>(dst + 8) = st.s8[1];
  } else if (blockIdx.x == 32) {
    const int t = threadIdx.x;               // 256 thr x 32 = 8192 elems
    const int col = t & 31, kb = (t >> 5) * 32;
#pragma unroll
    for (int i = 0; i < 32; i++)
      Web[(size_t)col * 256 + kb + i] = f2bf(We[(size_t)(kb + i) * NC + col]);
  } else {
    const int i = (blockIdx.x - 33) * 256 + threadIdx.x;   // 391*256 lanes
    if (i < NN) dc[i] = (1ULL << 44) | (1ULL << 32);       // self-loop
    for (int j = i; j < PKN; j += 391 * 256) pk[j] = 0;
  }
}

// ---- fused GEMM(1+2) + edge_deg --------------------------------------------
// blocks < GB: h2 = relu(relu(X@Ws+bs)@We+be); x0b=bf16(h2); out=t0*h2
//   (R13 verified path: H never hits HBM).
// blocks >= GB: edge-degree atomics (independent data; rides gemm's idle
//   issue slots and block tail — gemm is latency-bound at 28% occupancy).
__global__ __launch_bounds__(256, 3) void gemm_deg_kernel(
    const float* __restrict__ X, const unsigned short* __restrict__ Wt,
    const float* __restrict__ bias, const unsigned short* __restrict__ Web,
    const float* __restrict__ be, const float* __restrict__ temp,
    unsigned short* __restrict__ x0b, float* __restrict__ out,
    const int* __restrict__ ei, const float* __restrict__ ew, u64* dc) {
  constexpr int PAD = 36;
  __shared__ __align__(16) unsigned short Asm[2][64 * PAD];    //  9.2 KB
  __shared__ __align__(16) unsigned short Bsm[2][256 * PAD];   // 36.9 KB
  const int tid = threadIdx.x;

  if (blockIdx.x >= GB) {                    // ---- edge_deg path ----
    const int e = (blockIdx.x - GB) * 256 + tid;   // 6250*256 = EE exact
    if (e < EE) {
      const int col = ei[EE + e];
      u64 v = (1ULL << 44) | (u64)((double)ew[e] * 4294967296.0);
      atomicAdd(&dc[col], v);
    }
    return;
  }

  const int lane = tid & 63;
  const int w = tid >> 6;                    // wave = col strip (1x4 grid)
  const int l15 = lane & 15, kq = lane >> 4;
  const int m0 = blockIdx.x * 64;            // 64*1563 >= NN

  const int arl = tid >> 2, aq = tid & 3;
  int ar = m0 + arl; if (ar >= NN) ar = NN - 1;
  const float* aptr = X + (size_t)ar * NF + aq * 8;
  const int awr = arl * PAD + aq * 8;
  const unsigned short* bptr = Wt + (size_t)tid * NF;
  const int bwr = tid * PAD;

  f32x4 acc[4][4];
#pragma unroll
  for (int m = 0; m < 4; m++)
#pragma unroll
    for (int n = 0; n < 4; n++) acc[m][n] = (f32x4)0.0f;

  float4 ra[3][2]; short8 rb[3][4];          // depth-3 prefetch ring

#define LOADR(ks, j) do { \
    ra[j][0] = *reinterpret_cast<const float4*>(aptr + (ks) * 32); \
    ra[j][1] = *reinterpret_cast<const float4*>(aptr + (ks) * 32 + 4); \
    rb[j][0] = *reinterpret_cast<const short8*>(bptr + (ks) * 32); \
    rb[j][1] = *reinterpret_cast<const short8*>(bptr + (ks) * 32 + 8); \
    rb[j][2] = *reinterpret_cast<const short8*>(bptr + (ks) * 32 + 16); \
    rb[j][3] = *reinterpret_cast<const short8*>(bptr + (ks) * 32 + 24); \
  } while (0)

#define STAGE(b, j) do { \
    *reinterpret_cast<short8*>(&Asm[b][awr]) = cvt8(ra[j][0], ra[j][1]); \
    *reinterpret_cast<short8*>(&Bsm[b][bwr]) = rb[j][0]; \
    *reinterpret_cast<short8*>(&Bsm[b][bwr + 8]) = rb[j][1]; \
    *reinterpret_cast<short8*>(&Bsm[b][bwr + 16]) = rb[j][2]; \
    *reinterpret_cast<short8*>(&Bsm[b][bwr + 24]) = rb[j][3]; \
  } while (0)

#define COMPUTE(b) do { \
    short8 af[4], bfr[4]; \
    _Pragma("unroll") \
    for (int mi = 0; mi < 4; mi++) \
      af[mi] = *reinterpret_cast<const short8*>(&Asm[b][(mi * 16 + l15) * PAD + kq * 8]); \
    _Pragma("unroll") \
    for (int ni = 0; ni < 4; ni++) \
      bfr[ni] = *reinterpret_cast<const short8*>(&Bsm[b][(w * 64 + ni * 16 + l15) * PAD + kq * 8]); \
    _Pragma("unroll") \
    for (int mi = 0; mi < 4; mi++) \
      _Pragma("unroll") \
      for (int ni = 0; ni < 4; ni++) \
        acc[mi][ni] = __builtin_amdgcn_mfma_f32_16x16x32_bf16(af[mi], bfr[ni], acc[mi][ni], 0, 0, 0); \
  } while (0)

  LOADR(0, 0);
  LOADR(1, 1);
  LOADR(2, 2);
  STAGE(0, 0);
  block_sync_lds();

#pragma unroll
  for (int p = 0; p < 16; p++) {
    if (p + 3 < 16) LOADR(p + 3, (p + 3) % 3);
    COMPUTE(p & 1);
    if (p + 1 < 16) STAGE((p + 1) & 1, (p + 1) % 3);
    block_sync_lds();
  }
#undef LOADR
#undef STAGE
#undef COMPUTE

  // ---- fused gemm2 epilogue (verified R13 path) ----------------------------
  unsigned short* Ht = (unsigned short*)Bsm;
  f32x4 acc2[2];
  acc2[0] = (f32x4)0.0f; acc2[1] = (f32x4)0.0f;
  const unsigned short* wrow = Web + (size_t)l15 * 256 + kq * 8;
#pragma unroll
  for (int p2 = 0; p2 < 2; p2++) {
    block_sync_lds();
    if ((w >> 1) == p2) {
#pragma unroll
      for (int ni = 0; ni < 4; ni++) {
        const int colg = w * 64 + ni * 16 + l15;
        const float bsv = bias[colg];
        const int cl = colg - p2 * 128;
#pragma unroll
        for (int mi = 0; mi < 4; mi++)
#pragma unroll
          for (int i = 0; i < 4; i++) {
            const int row = mi * 16 + kq * 4 + i;
            const float v = acc[mi][ni][i] + bsv;
            Ht[row * 136 + cl] = f2bf(v > 0.f ? v : 0.f);
          }
      }
    }
    block_sync_lds();
    const unsigned short* hr = Ht + (size_t)(w * 16 + l15) * 136 + kq * 8;
#pragma unroll
    for (int ks = 0; ks < 4; ks++) {
      short8 a  = *reinterpret_cast<const short8*>(hr + ks * 32);
      short8 b0 = *reinterpret_cast<const short8*>(wrow + p2 * 128 + ks * 32);
      short8 b1 = *reinterpret_cast<const short8*>(wrow + 16 * 256 + p2 * 128 + ks * 32);
      acc2[0] = __builtin_amdgcn_mfma_f32_16x16x32_bf16(a, b0, acc2[0], 0, 0, 0);
      acc2[1] = __builtin_amdgcn_mfma_f32_16x16x32_bf16(a, b1, acc2[1], 0, 0, 0);
    }
  }
  const float t0 = temp[0];
#pragma unroll
  for (int nt = 0; nt < 2; nt++) {
    const int col = nt * 16 + l15;
    const float bv = be[col];
#pragma unroll
    for (int i = 0; i < 4; i++) {
      const int row = m0 + w * 16 + kq * 4 + i;
      if (row < NN) {
        float v = acc2[nt][i] + bv;
        v = v > 0.f ? v : 0.f;
        x0b[(size_t)row * NC + col] = f2bf(v);
        out[(size_t)row * NC + col] = t0 * v;
      }
    }
  }
}

// ---- dis + scan1 fused: cnt/dis from dc, block sums of padded counts -------
__global__ void dis_scan_kernel(const u64* __restrict__ dc, float* __restrict__ dis,
                                int* __restrict__ cnt, int* bsum) {
  __shared__ int ws[4];
  const int tid = threadIdx.x;
  int base = blockIdx.x * 1024 + tid * 4;
  int s = 0;
#pragma unroll
  for (int j = 0; j < 4; j++) {
    int i = base + j;
    if (i < NN) {
      u64 v = dc[i];
      int c = (int)(v >> 44);
      cnt[i] = c;
      float deg = (float)((double)(v & 0xFFFFFFFFFFFULL) * (1.0 / 4294967296.0));
      dis[i] = rsqrtf(deg);
      s += padc(c);
    }
  }
  for (int off = 32; off > 0; off >>= 1) s += __shfl_down(s, off);
  if ((tid & 63) == 0) ws[tid >> 6] = s;
  __syncthreads();
  if (tid == 0) bsum[blockIdx.x] = ws[0] + ws[1] + ws[2] + ws[3];
}

// scan3 with inlined scan2 (R14, verified)
__global__ void scan3_kernel(const int* __restrict__ cnt, const int* __restrict__ bsum,
                             int* offs, int* cursor) {
  __shared__ int wsum[4];
  __shared__ int bofs_s;
  const int tid = threadIdx.x;
  const int lane = tid & 63, wv = tid >> 6;
  if (tid == 0) {
    int run = 0;
    for (int i = 0; i < (int)blockIdx.x; i++) run += bsum[i];
    bofs_s = run;
    if (blockIdx.x == 0) {
      int tot = 0;
      for (int i = 0; i < 98; i++) tot += bsum[i];
      offs[NN] = tot;
    }
  }
  int base = blockIdx.x * 1024 + tid * 4;
  int v[4]; int s = 0;
#pragma unroll
  for (int j = 0; j < 4; j++) { int i = base + j; v[j] = (i < NN) ? padc(cnt[i]) : 0; s += v[j]; }
  int incl = s;
  for (int off = 1; off < 64; off <<= 1) {
    int t = __shfl_up(incl, off);
    if (lane >= off) incl += t;
  }
  if (lane == 63) wsum[wv] = incl;
  __syncthreads();
  int woff = bofs_s;
  for (int w = 0; w < wv; w++) woff += wsum[w];
  int excl = woff + incl - s;
#pragma unroll
  for (int j = 0; j < 4; j++) {
    int i = base + j;
    if (i < NN) { offs[i] = excl; cursor[i] = excl; }
    excl += v[j];
  }
}

// pk[slot]: low 32 = row index, high 32 = fp32 weight bits
__global__ void fill_kernel(const int* __restrict__ ei, const float* __restrict__ ew,
                            const float* __restrict__ dis, int* cursor,
                            u64* __restrict__ pk) {
  int t = blockIdx.x * 256 + threadIdx.x;
  if (t < EE) {
    int r = ei[t], c = ei[EE + t];
    int slot = atomicAdd(&cursor[c], 1);
    unsigned int wb = __float_as_uint(dis[r] * ew[t] * dis[c]);
    pk[slot] = (u64)(unsigned int)r | ((u64)wb << 32);
  } else if (t < EE + NN) {
    int i = t - EE;
    int slot = atomicAdd(&cursor[i], 1);
    float d = dis[i];
    unsigned int wb = __float_as_uint(d * d);
    pk[slot] = (u64)(unsigned int)i | ((u64)wb << 32);
  }
}

// ---- SpMM (bf16 xk): xout = A*xin (R12 shape, verified fastest) ------------
__global__ __launch_bounds__(256) void spmm_kernel(
    const int* __restrict__ offs, const u64* __restrict__ pk,
    const unsigned short* __restrict__ xin, unsigned short* __restrict__ xout) {
  const int tid = threadIdx.x;
  const int node = blockIdx.x * 32 + (tid >> 3);   // 3125*32 = 100000 exact
  const int fq = (tid & 7) * 4;                    // feature quad base
  const int s = offs[node], e = offs[node + 1];
  float a0 = 0.f, a1 = 0.f, a2 = 0.f, a3 = 0.f;
  for (int j = s; j < e; j += 8) {
    ulonglong2 p01 = *reinterpret_cast<const ulonglong2*>(pk + j);
    ulonglong2 p23 = *reinterpret_cast<const ulonglong2*>(pk + j + 2);
    ulonglong2 p45 = *reinterpret_cast<const ulonglong2*>(pk + j + 4);
    ulonglong2 p67 = *reinterpret_cast<const ulonglong2*>(pk + j + 6);
    const u64 p[8] = {p01.x, p01.y, p23.x, p23.y, p45.x, p45.y, p67.x, p67.y};
    u64 q[8];
#pragma unroll
    for (int i = 0; i < 8; i++)
      q[i] = *reinterpret_cast<const u64*>(xin + (size_t)(unsigned int)p[i] * NC + fq);
#pragma unroll
    for (int i = 0; i < 8; i++) {
      const float w = __uint_as_float((unsigned int)(p[i] >> 32));
      a0 += w * bf2f((unsigned short)(q[i]));
      a1 += w * bf2f((unsigned short)(q[i] >> 16));
      a2 += w * bf2f((unsigned short)(q[i] >> 32));
      a3 += w * bf2f((unsigned short)(q[i] >> 48));
    }
  }
  unsigned int lo, hi;
  asm("v_cvt_pk_bf16_f32 %0, %1, %2" : "=v"(lo) : "v"(a0), "v"(a1));
  asm("v_cvt_pk_bf16_f32 %0, %1, %2" : "=v"(hi) : "v"(a2), "v"(a3));
  *reinterpret_cast<u64*>(xout + (size_t)node * NC + fq) =
      (u64)lo | ((u64)hi << 32);
}

// ---- last SpMM fused with the weighted sum (R14, verified) -----------------
__global__ __launch_bounds__(256) void spmm_wsum_kernel(
    const int* __restrict__ offs, const u64* __restrict__ pk,
    const unsigned short* __restrict__ xin,        // = slice 8
    const unsigned short* __restrict__ SL,         // slices 0..7
    float* __restrict__ out, const float* __restrict__ temp) {
  const int tid = threadIdx.x;
  const int node = blockIdx.x * 32 + (tid >> 3);
  const int fq = (tid & 7) * 4;
  const int s = offs[node], e = offs[node + 1];
  float a0 = 0.f, a1 = 0.f, a2 = 0.f, a3 = 0.f;
  for (int j = s; j < e; j += 8) {
    ulonglong2 p01 = *reinterpret_cast<const ulonglong2*>(pk + j);
    ulonglong2 p23 = *reinterpret_cast<const ulonglong2*>(pk + j + 2);
    ulonglong2 p45 = *reinterpret_cast<const ulonglong2*>(pk + j + 4);
    ulonglong2 p67 = *reinterpret_cast<const ulonglong2*>(pk + j + 6);
    const u64 p[8] = {p01.x, p01.y, p23.x, p23.y, p45.x, p45.y, p67.x, p67.y};
    u64 q[8];
#pragma unroll
    for (int i = 0; i < 8; i++)
      q[i] = *reinterpret_cast<const u64*>(xin + (size_t)(unsigned int)p[i] * NC + fq);
#pragma unroll
    for (int i = 0; i < 8; i++) {
      const float w = __uint_as_float((unsigned int)(p[i] >> 32));
      a0 += w * bf2f((unsigned short)(q[i]));
      a1 += w * bf2f((unsigned short)(q[i] >> 16));
      a2 += w * bf2f((unsigned short)(q[i] >> 32));
      a3 += w * bf2f((unsigned short)(q[i] >> 48));
    }
  }
  const size_t ob = (size_t)node * NC + fq;
  float4 o = *reinterpret_cast<const float4*>(out + ob);
  const float t10 = temp[10];
  float r0 = o.x + t10 * a0, r1 = o.y + t10 * a1;
  float r2 = o.z + t10 * a2, r3 = o.w + t10 * a3;
#pragma unroll
  for (int k = 0; k < 8; k++) {
    const float tk = temp[k + 1];
    u64 q = *reinterpret_cast<const u64*>(SL + (size_t)k * NN * NC + ob);
    r0 += tk * bf2f((unsigned short)(q));
    r1 += tk * bf2f((unsigned short)(q >> 16));
    r2 += tk * bf2f((unsigned short)(q >> 32));
    r3 += tk * bf2f((unsigned short)(q >> 48));
  }
  {
    const float tk = temp[9];                      // slice 8 == xin
    u64 q = *reinterpret_cast<const u64*>(xin + ob);
    r0 += tk * bf2f((unsigned short)(q));
    r1 += tk * bf2f((unsigned short)(q >> 16));
    r2 += tk * bf2f((unsigned short)(q >> 32));
    r3 += tk * bf2f((unsigned short)(q >> 48));
  }
  *reinterpret_cast<float4*>(out + ob) = make_float4(r0, r1, r2, r3);
}

extern "C" void kernel_launch(void* const* d_in, const int* in_sizes, int n_in,
                              void* d_out, int out_size, void* d_ws, size_t ws_size,
                              hipStream_t stream) {
  const float* X    = (const float*)d_in[0];
  const float* EA   = (const float*)d_in[1];
  const float* Ws   = (const float*)d_in[2];
  const float* bs   = (const float*)d_in[3];
  const float* We   = (const float*)d_in[4];
  const float* be   = (const float*)d_in[5];
  const float* temp = (const float*)d_in[6];
  const int*   ei   = (const int*)d_in[7];
  float* out = (float*)d_out;

  size_t off = 0;
  auto alloc = [&](size_t n) { void* p = (char*)d_ws + off; off += (n + 255) & ~(size_t)255; return p; };
  unsigned short* Wt  = (unsigned short*)alloc((size_t)NF * NH * 2);   // 256 KB
  unsigned short* Web = (unsigned short*)alloc((size_t)NH * NC * 2);   // 16 KB
  unsigned short* SL  = (unsigned short*)alloc((size_t)NN * NH * 2);   // 51.2 MB = xk slices 0..7
  unsigned short* x0b = (unsigned short*)alloc((size_t)NN * NC * 2);   // 6.4 MB (fused gemm out)
  unsigned short* xk8 = (unsigned short*)alloc((size_t)NN * NC * 2);   // slice 8
  u64*   dc   = (u64*)alloc((size_t)NN * 8);                           // 800 KB
  float* dis  = (float*)alloc((size_t)NN * 4);
  int*   cnt  = (int*)alloc((size_t)NN * 4);
  int*   offs = (int*)alloc((size_t)(NN + 1) * 4);
  int*   cursor = (int*)alloc((size_t)NN * 4);
  int*   bsum = (int*)alloc(98 * 4);
  u64*   pk   = (u64*)alloc((size_t)PKN * 8);                          // 19.2 MB (padded)

  // prep: weight conversion + dc init + pk zero (one launch, all independent)
  prep_kernel<<<424, 256, 0, stream>>>(Ws, We, Wt, Web, dc, pk);

  // fused MLP front-end + edge-degree atomics (independent halves co-dispatch)
  gemm_deg_kernel<<<GB + 6250, 256, 0, stream>>>(X, Wt, bs, Web, be, temp,
                                                 x0b, out, ei, EA, dc);

  // CSR finish (padded by-col build; SpMM stays atomic-free)
  dis_scan_kernel<<<98, 256, 0, stream>>>(dc, dis, cnt, bsum);
  scan3_kernel<<<98, 256, 0, stream>>>(cnt, bsum, offs, cursor);
  fill_kernel<<<6641, 256, 0, stream>>>(ei, EA, dis, cursor, pk);

  // K=10 propagation; slices 0..7 in SL, slice 8 in xk8; last hop fused w/ sum
  auto slice = [&](int k) -> unsigned short* {
    return (k < 8) ? SL + (size_t)k * NN * NC : xk8;
  };
  const unsigned short* xin = x0b;
  for (int k = 0; k < KP - 1; k++) {
    spmm_kernel<<<3125, 256, 0, stream>>>(offs, pk, xin, slice(k));
    xin = slice(k);
  }
  spmm_wsum_kernel<<<3125, 256, 0, stream>>>(offs, pk, xk8, SL, out, temp);
}

// Round 16
// 475.096 us; speedup vs baseline: 4.4514x; 1.0615x over previous
//
#include <hip/hip_runtime.h>

typedef __attribute__((ext_vector_type(8))) short short8;
typedef __attribute__((ext_vector_type(4))) float f32x4;
typedef unsigned long long u64;

constexpr int NN = 100000;
constexpr int EE = 1600000;
constexpr int NF = 512;
constexpr int NH = 256;
constexpr int NC = 32;
constexpr int KP = 10;
constexpr int PKN = EE + 8 * NN;   // padded pk entries
constexpr int GB = 782;            // gemm blocks (128 rows each): 782*128 >= NN

__device__ __forceinline__ unsigned short f2bf(float f) {
  unsigned int u = __float_as_uint(f);
  u += 0x7FFFu + ((u >> 16) & 1u);   // round-to-nearest-even
  return (unsigned short)(u >> 16);
}
__device__ __forceinline__ float bf2f(unsigned short s) {
  return __uint_as_float(((unsigned int)s) << 16);
}
// pad to 8: whole number of 8-batches in spmm
__device__ __forceinline__ int padc(int c) { return (c + 7) & ~7; }

__device__ __forceinline__ short8 cvt8(float4 a0, float4 a1) {
  union { unsigned int u[4]; short8 s; } r;
  asm("v_cvt_pk_bf16_f32 %0, %1, %2" : "=v"(r.u[0]) : "v"(a0.x), "v"(a0.y));
  asm("v_cvt_pk_bf16_f32 %0, %1, %2" : "=v"(r.u[1]) : "v"(a0.z), "v"(a0.w));
  asm("v_cvt_pk_bf16_f32 %0, %1, %2" : "=v"(r.u[2]) : "v"(a1.x), "v"(a1.y));
  asm("v_cvt_pk_bf16_f32 %0, %1, %2" : "=v"(r.u[3]) : "v"(a1.z), "v"(a1.w));
  return r.s;
}

// Barrier with LDS-only drain: keeps global loads (into registers) in flight
// across the barrier — avoids the compiler's vmcnt(0) drain of __syncthreads.
__device__ __forceinline__ void block_sync_lds() {
  asm volatile("s_waitcnt lgkmcnt(0)" ::: "memory");
  __builtin_amdgcn_s_barrier();
}

// ---- prep: weight conversion + dc init + pk zero (all independent) ---------
// blocks 0..31: Ws transpose tiles; block 32: Web; blocks 33..423: dc + pk.
__global__ void prep_kernel(const float* __restrict__ Ws, const float* __restrict__ We,
                            unsigned short* __restrict__ Wt, unsigned short* __restrict__ Web,
                            u64* __restrict__ dc, u64* __restrict__ pk) {
  if (blockIdx.x < 32) {
    __shared__ float tile[64][65];
    const int k0 = (blockIdx.x >> 2) * 64;   // 8 k-tiles
    const int c0 = (blockIdx.x & 3) * 64;    // 4 col-tiles
    const int t = threadIdx.x;
    const int g = t >> 6, l = t & 63;
#pragma unroll
    for (int j = 0; j < 16; j++) {
      const int row = g * 16 + j;
      tile[row][l] = Ws[(size_t)(k0 + row) * NH + c0 + l];
    }
    __syncthreads();
    const int col = t >> 2, ks = (t & 3) * 16;
    union { unsigned short us[16]; short8 s8[2]; } st;
#pragma unroll
    for (int i = 0; i < 16; i++) st.us[i] = f2bf(tile[ks + i][col]);
    unsigned short* dst = Wt + (size_t)(c0 + col) * NF + k0 + ks;
    *reinterpret_cast<short8*>(dst) = st.s8[0];
    *reinterpret_cast<short8*>(dst + 8) = st.s8[1];
  } else if (blockIdx.x == 32) {
    const int t = threadIdx.x;               // 256 thr x 32 = 8192 elems
    const int col = t & 31, kb = (t >> 5) * 32;
#pragma unroll
    for (int i = 0; i < 32; i++)
      Web[(size_t)col * 256 + kb + i] = f2bf(We[(size_t)(kb + i) * NC + col]);
  } else {
    const int i = (blockIdx.x - 33) * 256 + threadIdx.x;   // 391*256 lanes
    if (i < NN) dc[i] = (1ULL << 44) | (1ULL << 32);       // self-loop
    for (int j = i; j < PKN; j += 391 * 256) pk[j] = 0;
  }
}

// ---- fused GEMM(1+2) + edge_deg --------------------------------------------
// blocks < GB: 128x256 tile, 512 thr = 8 waves (2x4), wave tile 64x64, BK=32,
//   PAD=36, depth-3 reg ring, lgkm-only barriers (verified skeleton, scaled
//   for 2 blocks/CU x 8 waves = 16 waves/CU vs 12 before).
//   h2 = relu(relu(X@Ws+bs)@We+be); x0b=bf16(h2); out=t0*h2 (H never in HBM).
// blocks >= GB: edge-degree atomics (independent data; backfills gemm's idle
//   slots and block tail — R15-verified co-dispatch).
__global__ __launch_bounds__(512, 2) void gemm_deg_kernel(
    const float* __restrict__ X, const unsigned short* __restrict__ Wt,
    const float* __restrict__ bias, const unsigned short* __restrict__ Web,
    const float* __restrict__ be, const float* __restrict__ temp,
    unsigned short* __restrict__ x0b, float* __restrict__ out,
    const int* __restrict__ ei, const float* __restrict__ ew, u64* dc) {
  constexpr int PAD = 36;
  __shared__ __align__(16) unsigned short Asm[2][128 * PAD];   // 18.4 KB
  __shared__ __align__(16) unsigned short Bsm[2][256 * PAD];   // 36.9 KB
  const int tid = threadIdx.x;

  if (blockIdx.x >= GB) {                    // ---- edge_deg path ----
    const int e = (blockIdx.x - GB) * 512 + tid;   // 3125*512 = EE exact
    if (e < EE) {
      const int col = ei[EE + e];
      u64 v = (1ULL << 44) | (u64)((double)ew[e] * 4294967296.0);
      atomicAdd(&dc[col], v);
    }
    return;
  }

  const int lane = tid & 63;
  const int w = tid >> 6;                    // 8 waves: wm=w>>2 (row), wn=w&3 (col)
  const int wm = w >> 2, wn = w & 3;
  const int l15 = lane & 15, kq = lane >> 4;
  const int m0 = blockIdx.x * 128;

  // A staging: 4 threads/row (8 floats each), 128 rows
  const int arl = tid >> 2, aq = tid & 3;
  int ar = m0 + arl; if (ar >= NN) ar = NN - 1;
  const float* aptr = X + (size_t)ar * NF + aq * 8;
  const int awr = arl * PAD + aq * 8;
  // B staging: 2 threads/col, 16 ushorts each (full 32-k column per phase)
  const int bcl = tid >> 1, bh = tid & 1;
  const unsigned short* bptr = Wt + (size_t)bcl * NF + bh * 16;
  const int bwr = bcl * PAD + bh * 16;

  f32x4 acc[4][4];
#pragma unroll
  for (int m = 0; m < 4; m++)
#pragma unroll
    for (int n = 0; n < 4; n++) acc[m][n] = (f32x4)0.0f;

  float4 ra[3][2]; short8 rb[3][2];          // depth-3 prefetch ring

#define LOADR(ks, j) do { \
    ra[j][0] = *reinterpret_cast<const float4*>(aptr + (ks) * 32); \
    ra[j][1] = *reinterpret_cast<const float4*>(aptr + (ks) * 32 + 4); \
    rb[j][0] = *reinterpret_cast<const short8*>(bptr + (ks) * 32); \
    rb[j][1] = *reinterpret_cast<const short8*>(bptr + (ks) * 32 + 8); \
  } while (0)

#define STAGE(b, j) do { \
    *reinterpret_cast<short8*>(&Asm[b][awr]) = cvt8(ra[j][0], ra[j][1]); \
    *reinterpret_cast<short8*>(&Bsm[b][bwr]) = rb[j][0]; \
    *reinterpret_cast<short8*>(&Bsm[b][bwr + 8]) = rb[j][1]; \
  } while (0)

#define COMPUTE(b) do { \
    short8 af[4], bfr[4]; \
    _Pragma("unroll") \
    for (int mi = 0; mi < 4; mi++) \
      af[mi] = *reinterpret_cast<const short8*>(&Asm[b][(wm * 64 + mi * 16 + l15) * PAD + kq * 8]); \
    _Pragma("unroll") \
    for (int ni = 0; ni < 4; ni++) \
      bfr[ni] = *reinterpret_cast<const short8*>(&Bsm[b][(wn * 64 + ni * 16 + l15) * PAD + kq * 8]); \
    _Pragma("unroll") \
    for (int mi = 0; mi < 4; mi++) \
      _Pragma("unroll") \
      for (int ni = 0; ni < 4; ni++) \
        acc[mi][ni] = __builtin_amdgcn_mfma_f32_16x16x32_bf16(af[mi], bfr[ni], acc[mi][ni], 0, 0, 0); \
  } while (0)

  LOADR(0, 0);
  LOADR(1, 1);
  LOADR(2, 2);
  STAGE(0, 0);
  block_sync_lds();

#pragma unroll
  for (int p = 0; p < 16; p++) {
    if (p + 3 < 16) LOADR(p + 3, (p + 3) % 3);
    COMPUTE(p & 1);
    if (p + 1 < 16) STAGE((p + 1) & 1, (p + 1) % 3);
    block_sync_lds();
  }
#undef LOADR
#undef STAGE
#undef COMPUTE

  // ---- fused gemm2 epilogue.  C/D layout: col=lane&15, row=(lane>>4)*4+i --
  // Ht overlays Bsm (dead after main loop): 128 x 136 bf16 = 34.8 KB.
  // 2 passes over col halves; waves with (wn>>1)==p2 write their cols.
  unsigned short* Ht = (unsigned short*)Bsm;
  f32x4 acc2[2];
  acc2[0] = (f32x4)0.0f; acc2[1] = (f32x4)0.0f;
  const unsigned short* wrow = Web + (size_t)l15 * 256 + kq * 8;
#pragma unroll
  for (int p2 = 0; p2 < 2; p2++) {
    block_sync_lds();
    if ((wn >> 1) == p2) {
#pragma unroll
      for (int ni = 0; ni < 4; ni++) {
        const int colg = wn * 64 + ni * 16 + l15;
        const float bsv = bias[colg];
        const int cl = colg - p2 * 128;
#pragma unroll
        for (int mi = 0; mi < 4; mi++)
#pragma unroll
          for (int i = 0; i < 4; i++) {
            const int row = wm * 64 + mi * 16 + kq * 4 + i;
            const float v = acc[mi][ni][i] + bsv;
            Ht[row * 136 + cl] = f2bf(v > 0.f ? v : 0.f);
          }
      }
    }
    block_sync_lds();
    const unsigned short* hr = Ht + (size_t)(w * 16 + l15) * 136 + kq * 8;
#pragma unroll
    for (int ks = 0; ks < 4; ks++) {
      short8 a  = *reinterpret_cast<const short8*>(hr + ks * 32);
      short8 b0 = *reinterpret_cast<const short8*>(wrow + p2 * 128 + ks * 32);
      short8 b1 = *reinterpret_cast<const short8*>(wrow + 16 * 256 + p2 * 128 + ks * 32);
      acc2[0] = __builtin_amdgcn_mfma_f32_16x16x32_bf16(a, b0, acc2[0], 0, 0, 0);
      acc2[1] = __builtin_amdgcn_mfma_f32_16x16x32_bf16(a, b1, acc2[1], 0, 0, 0);
    }
  }
  const float t0 = temp[0];
#pragma unroll
  for (int nt = 0; nt < 2; nt++) {
    const int col = nt * 16 + l15;
    const float bv = be[col];
#pragma unroll
    for (int i = 0; i < 4; i++) {
      const int row = m0 + w * 16 + kq * 4 + i;
      if (row < NN) {
        float v = acc2[nt][i] + bv;
        v = v > 0.f ? v : 0.f;
        x0b[(size_t)row * NC + col] = f2bf(v);
        out[(size_t)row * NC + col] = t0 * v;
      }
    }
  }
}

// ---- dis + scan1 fused: cnt/dis from dc, block sums of padded counts -------
__global__ void dis_scan_kernel(const u64* __restrict__ dc, float* __restrict__ dis,
                                int* __restrict__ cnt, int* bsum) {
  __shared__ int ws[4];
  const int tid = threadIdx.x;
  int base = blockIdx.x * 1024 + tid * 4;
  int s = 0;
#pragma unroll
  for (int j = 0; j < 4; j++) {
    int i = base + j;
    if (i < NN) {
      u64 v = dc[i];
      int c = (int)(v >> 44);
      cnt[i] = c;
      float deg = (float)((double)(v & 0xFFFFFFFFFFFULL) * (1.0 / 4294967296.0));
      dis[i] = rsqrtf(deg);
      s += padc(c);
    }
  }
  for (int off = 32; off > 0; off >>= 1) s += __shfl_down(s, off);
  if ((tid & 63) == 0) ws[tid >> 6] = s;
  __syncthreads();
  if (tid == 0) bsum[blockIdx.x] = ws[0] + ws[1] + ws[2] + ws[3];
}

// scan3 with inlined scan2 (R14, verified)
__global__ void scan3_kernel(const int* __restrict__ cnt, const int* __restrict__ bsum,
                             int* offs, int* cursor) {
  __shared__ int wsum[4];
  __shared__ int bofs_s;
  const int tid = threadIdx.x;
  const int lane = tid & 63, wv = tid >> 6;
  if (tid == 0) {
    int run = 0;
    for (int i = 0; i < (int)blockIdx.x; i++) run += bsum[i];
    bofs_s = run;
    if (blockIdx.x == 0) {
      int tot = 0;
      for (int i = 0; i < 98; i++) tot += bsum[i];
      offs[NN] = tot;
    }
  }
  int base = blockIdx.x * 1024 + tid * 4;
  int v[4]; int s = 0;
#pragma unroll
  for (int j = 0; j < 4; j++) { int i = base + j; v[j] = (i < NN) ? padc(cnt[i]) : 0; s += v[j]; }
  int incl = s;
  for (int off = 1; off < 64; off <<= 1) {
    int t = __shfl_up(incl, off);
    if (lane >= off) incl += t;
  }
  if (lane == 63) wsum[wv] = incl;
  __syncthreads();
  int woff = bofs_s;
  for (int w = 0; w < wv; w++) woff += wsum[w];
  int excl = woff + incl - s;
#pragma unroll
  for (int j = 0; j < 4; j++) {
    int i = base + j;
    if (i < NN) { offs[i] = excl; cursor[i] = excl; }
    excl += v[j];
  }
}

// pk[slot]: low 32 = row index, high 32 = fp32 weight bits
__global__ void fill_kernel(const int* __restrict__ ei, const float* __restrict__ ew,
                            const float* __restrict__ dis, int* cursor,
                            u64* __restrict__ pk) {
  int t = blockIdx.x * 256 + threadIdx.x;
  if (t < EE) {
    int r = ei[t], c = ei[EE + t];
    int slot = atomicAdd(&cursor[c], 1);
    unsigned int wb = __float_as_uint(dis[r] * ew[t] * dis[c]);
    pk[slot] = (u64)(unsigned int)r | ((u64)wb << 32);
  } else if (t < EE + NN) {
    int i = t - EE;
    int slot = atomicAdd(&cursor[i], 1);
    float d = dis[i];
    unsigned int wb = __float_as_uint(d * d);
    pk[slot] = (u64)(unsigned int)i | ((u64)wb << 32);
  }
}

// ---- SpMM (bf16 xk): xout = A*xin (R12 shape, verified fastest) ------------
__global__ __launch_bounds__(256) void spmm_kernel(
    const int* __restrict__ offs, const u64* __restrict__ pk,
    const unsigned short* __restrict__ xin, unsigned short* __restrict__ xout) {
  const int tid = threadIdx.x;
  const int node = blockIdx.x * 32 + (tid >> 3);   // 3125*32 = 100000 exact
  const int fq = (tid & 7) * 4;                    // feature quad base
  const int s = offs[node], e = offs[node + 1];
  float a0 = 0.f, a1 = 0.f, a2 = 0.f, a3 = 0.f;
  for (int j = s; j < e; j += 8) {
    ulonglong2 p01 = *reinterpret_cast<const ulonglong2*>(pk + j);
    ulonglong2 p23 = *reinterpret_cast<const ulonglong2*>(pk + j + 2);
    ulonglong2 p45 = *reinterpret_cast<const ulonglong2*>(pk + j + 4);
    ulonglong2 p67 = *reinterpret_cast<const ulonglong2*>(pk + j + 6);
    const u64 p[8] = {p01.x, p01.y, p23.x, p23.y, p45.x, p45.y, p67.x, p67.y};
    u64 q[8];
#pragma unroll
    for (int i = 0; i < 8; i++)
      q[i] = *reinterpret_cast<const u64*>(xin + (size_t)(unsigned int)p[i] * NC + fq);
#pragma unroll
    for (int i = 0; i < 8; i++) {
      const float w = __uint_as_float((unsigned int)(p[i] >> 32));
      a0 += w * bf2f((unsigned short)(q[i]));
      a1 += w * bf2f((unsigned short)(q[i] >> 16));
      a2 += w * bf2f((unsigned short)(q[i] >> 32));
      a3 += w * bf2f((unsigned short)(q[i] >> 48));
    }
  }
  unsigned int lo, hi;
  asm("v_cvt_pk_bf16_f32 %0, %1, %2" : "=v"(lo) : "v"(a0), "v"(a1));
  asm("v_cvt_pk_bf16_f32 %0, %1, %2" : "=v"(hi) : "v"(a2), "v"(a3));
  *reinterpret_cast<u64*>(xout + (size_t)node * NC + fq) =
      (u64)lo | ((u64)hi << 32);
}

// ---- last SpMM fused with the weighted sum (R14, verified) -----------------
__global__ __launch_bounds__(256) void spmm_wsum_kernel(
    const int* __restrict__ offs, const u64* __restrict__ pk,
    const unsigned short* __restrict__ xin,        // = slice 8
    const unsigned short* __restrict__ SL,         // slices 0..7
    float* __restrict__ out, const float* __restrict__ temp) {
  const int tid = threadIdx.x;
  const int node = blockIdx.x * 32 + (tid >> 3);
  const int fq = (tid & 7) * 4;
  const int s = offs[node], e = offs[node + 1];
  float a0 = 0.f, a1 = 0.f, a2 = 0.f, a3 = 0.f;
  for (int j = s; j < e; j += 8) {
    ulonglong2 p01 = *reinterpret_cast<const ulonglong2*>(pk + j);
    ulonglong2 p23 = *reinterpret_cast<const ulonglong2*>(pk + j + 2);
    ulonglong2 p45 = *reinterpret_cast<const ulonglong2*>(pk + j + 4);
    ulonglong2 p67 = *reinterpret_cast<const ulonglong2*>(pk + j + 6);
    const u64 p[8] = {p01.x, p01.y, p23.x, p23.y, p45.x, p45.y, p67.x, p67.y};
    u64 q[8];
#pragma unroll
    for (int i = 0; i < 8; i++)
      q[i] = *reinterpret_cast<const u64*>(xin + (size_t)(unsigned int)p[i] * NC + fq);
#pragma unroll
    for (int i = 0; i < 8; i++) {
      const float w = __uint_as_float((unsigned int)(p[i] >> 32));
      a0 += w * bf2f((unsigned short)(q[i]));
      a1 += w * bf2f((unsigned short)(q[i] >> 16));
      a2 += w * bf2f((unsigned short)(q[i] >> 32));
      a3 += w * bf2f((unsigned short)(q[i] >> 48));
    }
  }
  const size_t ob = (size_t)node * NC + fq;
  float4 o = *reinterpret_cast<const float4*>(out + ob);
  const float t10 = temp[10];
  float r0 = o.x + t10 * a0, r1 = o.y + t10 * a1;
  float r2 = o.z + t10 * a2, r3 = o.w + t10 * a3;
#pragma unroll
  for (int k = 0; k < 8; k++) {
    const float tk = temp[k + 1];
    u64 q = *reinterpret_cast<const u64*>(SL + (size_t)k * NN * NC + ob);
    r0 += tk * bf2f((unsigned short)(q));
    r1 += tk * bf2f((unsigned short)(q >> 16));
    r2 += tk * bf2f((unsigned short)(q >> 32));
    r3 += tk * bf2f((unsigned short)(q >> 48));
  }
  {
    const float tk = temp[9];                      // slice 8 == xin
    u64 q = *reinterpret_cast<const u64*>(xin + ob);
    r0 += tk * bf2f((unsigned short)(q));
    r1 += tk * bf2f((unsigned short)(q >> 16));
    r2 += tk * bf2f((unsigned short)(q >> 32));
    r3 += tk * bf2f((unsigned short)(q >> 48));
  }
  *reinterpret_cast<float4*>(out + ob) = make_float4(r0, r1, r2, r3);
}

extern "C" void kernel_launch(void* const* d_in, const int* in_sizes, int n_in,
                              void* d_out, int out_size, void* d_ws, size_t ws_size,
                              hipStream_t stream) {
  const float* X    = (const float*)d_in[0];
  const float* EA   = (const float*)d_in[1];
  const float* Ws   = (const float*)d_in[2];
  const float* bs   = (const float*)d_in[3];
  const float* We   = (const float*)d_in[4];
  const float* be   = (const float*)d_in[5];
  const float* temp = (const float*)d_in[6];
  const int*   ei   = (const int*)d_in[7];
  float* out = (float*)d_out;

  size_t off = 0;
  auto alloc = [&](size_t n) { void* p = (char*)d_ws + off; off += (n + 255) & ~(size_t)255; return p; };
  unsigned short* Wt  = (unsigned short*)alloc((size_t)NF * NH * 2);   // 256 KB
  unsigned short* Web = (unsigned short*)alloc((size_t)NH * NC * 2);   // 16 KB
  unsigned short* SL  = (unsigned short*)alloc((size_t)NN * NH * 2);   // 51.2 MB = xk slices 0..7
  unsigned short* x0b = (unsigned short*)alloc((size_t)NN * NC * 2);   // 6.4 MB (fused gemm out)
  unsigned short* xk8 = (unsigned short*)alloc((size_t)NN * NC * 2);   // slice 8
  u64*   dc   = (u64*)alloc((size_t)NN * 8);                           // 800 KB
  float* dis  = (float*)alloc((size_t)NN * 4);
  int*   cnt  = (int*)alloc((size_t)NN * 4);
  int*   offs = (int*)alloc((size_t)(NN + 1) * 4);
  int*   cursor = (int*)alloc((size_t)NN * 4);
  int*   bsum = (int*)alloc(98 * 4);
  u64*   pk   = (u64*)alloc((size_t)PKN * 8);                          // 19.2 MB (padded)

  // prep: weight conversion + dc init + pk zero (one launch, all independent)
  prep_kernel<<<424, 256, 0, stream>>>(Ws, We, Wt, Web, dc, pk);

  // fused MLP front-end + edge-degree atomics (independent halves co-dispatch)
  gemm_deg_kernel<<<GB + 3125, 512, 0, stream>>>(X, Wt, bs, Web, be, temp,
                                                 x0b, out, ei, EA, dc);

  // CSR finish (padded by-col build; SpMM stays atomic-free)
  dis_scan_kernel<<<98, 256, 0, stream>>>(dc, dis, cnt, bsum);
  scan3_kernel<<<98, 256, 0, stream>>>(cnt, bsum, offs, cursor);
  fill_kernel<<<6641, 256, 0, stream>>>(ei, EA, dis, cursor, pk);

  // K=10 propagation; slices 0..7 in SL, slice 8 in xk8; last hop fused w/ sum
  auto slice = [&](int k) -> unsigned short* {
    return (k < 8) ? SL + (size_t)k * NN * NC : xk8;
  };
  const unsigned short* xin = x0b;
  for (int k = 0; k < KP - 1; k++) {
    spmm_kernel<<<3125, 256, 0, stream>>>(offs, pk, xin, slice(k));
    xin = slice(k);
  }
  spmm_wsum_kernel<<<3125, 256, 0, stream>>>(offs, pk, xk8, SL, out, temp);
}